// Round 15
// baseline (803.111 us; speedup 1.0000x reference)
//
#include <hip/hip_runtime.h>
#include <math.h>

#define EPSBN 1e-5f

typedef __attribute__((ext_vector_type(4))) float f32x4;
typedef __attribute__((ext_vector_type(8))) short s16x8;

__device__ __forceinline__ unsigned short f2bf(float f) {
    unsigned u = __builtin_bit_cast(unsigned, f);
    u = (u + 0x7fffu + ((u >> 16) & 1u)) >> 16;
    return (unsigned short)u;
}
__device__ __forceinline__ float bf2f(unsigned short s) {
    unsigned u = ((unsigned)s) << 16;
    return __builtin_bit_cast(float, u);
}

// ---------------- workspace layout (BYTE offsets), peak 56,054,016 B ----------------
// W @0 | WF @372,992 | W3F @2,732,288 | SC @3,027,200 | BF @3,551,488
// A2H @5,648,640 | A2L @22,425,856 | A3P @39,203,072 | W2F @55,980,288

__global__ __launch_bounds__(256) void prep_k(
    const float* __restrict__ w1, const float* __restrict__ b1, const float* __restrict__ g1,
    const float* __restrict__ be1, const float* __restrict__ m1, const float* __restrict__ v1,
    const float* __restrict__ w2, const float* __restrict__ b2, const float* __restrict__ g2,
    const float* __restrict__ be2, const float* __restrict__ m2, const float* __restrict__ v2,
    const float* __restrict__ w3, const float* __restrict__ b3, const float* __restrict__ g3,
    const float* __restrict__ be3, const float* __restrict__ m3, const float* __restrict__ v3,
    float* __restrict__ W)
{
    int i = blockIdx.x * 256 + threadIdx.x;
    if (i < 864) {
        int co = i & 31; int r = i >> 5; int ci = r % 3; int kk = r / 3;
        float A = g1[co] * rsqrtf(v1[co] + EPSBN);
        W[i] = w1[(co*3 + ci)*9 + kk] * A;
    } else if (i < 896) {
        int co = i - 864;
        float A = g1[co] * rsqrtf(v1[co] + EPSBN);
        W[i] = (b1[co] - m1[co]) * A + be1[co];
    } else if (i >= 19328 && i < 19392) {
        int co = i - 19328;
        float A = g2[co] * rsqrtf(v2[co] + EPSBN);
        W[i] = (b2[co] - m2[co]) * A + be2[co];
    } else if (i >= 93120 && i < 93248) {
        int co = i - 93120;
        float A = g3[co] * rsqrtf(v3[co] + EPSBN);
        W[i] = (b3[co] - m3[co]) * A + be3[co];
    }
}

__global__ __launch_bounds__(256) void prep2_k(
    const float* __restrict__ dw1, const float* __restrict__ bw1,
    unsigned short* __restrict__ WF)
{
    int i = blockIdx.x * 256 + threadIdx.x;
    if (i >= 1179648) return;
    int head = i / 589824;
    int r    = i - head * 589824;
    int kk   = r >> 16;
    int r2   = r & 65535;
    int cig  = r2 >> 14;
    int pl   = (r2 >> 13) & 1;
    int nf   = (r2 >> 9) & 15;
    int lane = (r2 >> 3) & 63;
    int j    = r2 & 7;
    int ci = cig*32 + (lane >> 4)*8 + j;
    int co = (lane & 15) + nf*16;
    const float* src = head ? bw1 : dw1;
    float w = src[(co*128 + ci)*9 + kk];
    unsigned short h = f2bf(w);
    WF[i] = pl ? f2bf(w - bf2f(h)) : h;
}

__global__ __launch_bounds__(256) void prep3_k(
    const float* __restrict__ w3, const float* __restrict__ g3, const float* __restrict__ v3,
    unsigned short* __restrict__ W3F)
{
    int i = blockIdx.x * 256 + threadIdx.x;
    if (i >= 147456) return;
    int kk = i >> 14;
    int r  = i & 16383;
    int cig = r >> 13;
    int pl  = (r >> 12) & 1;
    int nf  = (r >> 9) & 7;
    int lane = (r >> 3) & 63;
    int j   = r & 7;
    int ci = cig*32 + (lane >> 4)*8 + j;
    int co = nf*16 + (lane & 15);
    float A = g3[co] * rsqrtf(v3[co] + EPSBN);
    float w = w3[(co*64 + ci)*9 + kk] * A;
    unsigned short h = f2bf(w);
    W3F[i] = pl ? f2bf(w - bf2f(h)) : h;
}

__global__ __launch_bounds__(256) void prep4_k(
    const float* __restrict__ w2, const float* __restrict__ g2, const float* __restrict__ v2,
    unsigned short* __restrict__ W2F)
{
    int i = blockIdx.x * 256 + threadIdx.x;
    if (i >= 36864) return;
    int kk = i >> 12;
    int r  = i & 4095;
    int pl  = r >> 11;
    int nfg = (r >> 9) & 3;
    int lane = (r >> 3) & 63;
    int j   = r & 7;
    int ci = (lane >> 4)*8 + j;
    int co = nfg*16 + (lane & 15);
    float A = g2[co] * rsqrtf(v2[co] + EPSBN);
    float w = w2[(co*32 + ci)*9 + kk] * A;
    unsigned short h = f2bf(w);
    W2F[i] = pl ? f2bf(w - bf2f(h)) : h;
}

__global__ __launch_bounds__(256, 4) void conv12mm_k(
    const float* __restrict__ x, const float* __restrict__ W,
    const unsigned short* __restrict__ W2F,
    unsigned short* __restrict__ A2H, unsigned short* __restrict__ A2L, int b0)
{
    __shared__ __attribute__((aligned(16))) unsigned short Ah[9792];
    __shared__ __attribute__((aligned(16))) unsigned short Al[9792];

    const int tid  = threadIdx.x;
    const int lane = tid & 63;
    const int wv   = tid >> 6;
    const int m    = lane & 15;
    const int ks   = lane >> 4;

    const int bl   = blockIdx.x >> 8;
    const int tile = blockIdx.x & 255;
    const int OY = (tile >> 3) * 4;
    const int OX = (tile & 7) * 16;
    const int base1y = 2*OY - 1, base1x = 2*OX - 1;

    const float* xb = x + (size_t)(b0 + bl) * 3 * 262144;

    for (int t = tid; t < 297; t += 256) {
        int row = t / 33, lx = t - row*33;
        int y1 = base1y + row, x1 = base1x + lx;
        float c1[32];
        #pragma unroll
        for (int c = 0; c < 32; c++) c1[c] = 0.f;
        if (((unsigned)y1 < 256u) && ((unsigned)x1 < 256u)) {
            #pragma unroll
            for (int ky = 0; ky < 3; ky++) {
                int xy = 2*y1 + ky - 1;
                if ((unsigned)xy < 512u) {
                    #pragma unroll
                    for (int kx = 0; kx < 3; kx++) {
                        int xx = 2*x1 + kx - 1;
                        if ((unsigned)xx < 512u) {
                            int kk = ky*3 + kx;
                            #pragma unroll
                            for (int ci = 0; ci < 3; ci++) {
                                float v = xb[(size_t)ci*262144 + xy*512 + xx];
                                const float4* w4 = (const float4*)(W + (kk*3+ci)*32);
                                float4 wa = w4[0], wb = w4[1], wc = w4[2], wd = w4[3];
                                float4 we = w4[4], wf = w4[5], wg = w4[6], wh = w4[7];
                                c1[0]  = fmaf(v, wa.x, c1[0]);  c1[1]  = fmaf(v, wa.y, c1[1]);
                                c1[2]  = fmaf(v, wa.z, c1[2]);  c1[3]  = fmaf(v, wa.w, c1[3]);
                                c1[4]  = fmaf(v, wb.x, c1[4]);  c1[5]  = fmaf(v, wb.y, c1[5]);
                                c1[6]  = fmaf(v, wb.z, c1[6]);  c1[7]  = fmaf(v, wb.w, c1[7]);
                                c1[8]  = fmaf(v, wc.x, c1[8]);  c1[9]  = fmaf(v, wc.y, c1[9]);
                                c1[10] = fmaf(v, wc.z, c1[10]); c1[11] = fmaf(v, wc.w, c1[11]);
                                c1[12] = fmaf(v, wd.x, c1[12]); c1[13] = fmaf(v, wd.y, c1[13]);
                                c1[14] = fmaf(v, wd.z, c1[14]); c1[15] = fmaf(v, wd.w, c1[15]);
                                c1[16] = fmaf(v, we.x, c1[16]); c1[17] = fmaf(v, we.y, c1[17]);
                                c1[18] = fmaf(v, we.z, c1[18]); c1[19] = fmaf(v, we.w, c1[19]);
                                c1[20] = fmaf(v, wf.x, c1[20]); c1[21] = fmaf(v, wf.y, c1[21]);
                                c1[22] = fmaf(v, wf.z, c1[22]); c1[23] = fmaf(v, wf.w, c1[23]);
                                c1[24] = fmaf(v, wg.x, c1[24]); c1[25] = fmaf(v, wg.y, c1[25]);
                                c1[26] = fmaf(v, wg.z, c1[26]); c1[27] = fmaf(v, wg.w, c1[27]);
                                c1[28] = fmaf(v, wh.x, c1[28]); c1[29] = fmaf(v, wh.y, c1[29]);
                                c1[30] = fmaf(v, wh.z, c1[30]); c1[31] = fmaf(v, wh.w, c1[31]);
                            }
                        }
                    }
                }
            }
            #pragma unroll
            for (int c = 0; c < 32; c++)
                c1[c] = fmaxf(c1[c] + W[864 + c], 0.f);
        }
        int xi = (lx & 1)*17 + (lx >> 1);
        #pragma unroll
        for (int kg = 0; kg < 4; kg++) {
            uint4 h, l;
            unsigned hw[4], lw[4];
            #pragma unroll
            for (int q = 0; q < 4; q++) {
                float r0 = c1[kg*8 + 2*q], r1 = c1[kg*8 + 2*q + 1];
                unsigned short h0 = f2bf(r0), h1 = f2bf(r1);
                unsigned short l0 = f2bf(r0 - bf2f(h0)), l1 = f2bf(r1 - bf2f(h1));
                hw[q] = (unsigned)h0 | ((unsigned)h1 << 16);
                lw[q] = (unsigned)l0 | ((unsigned)l1 << 16);
            }
            h.x = hw[0]; h.y = hw[1]; h.z = hw[2]; h.w = hw[3];
            l.x = lw[0]; l.y = lw[1]; l.z = lw[2]; l.w = lw[3];
            int a = ((kg*9 + row)*34 + xi)*8;
            *(uint4*)&Ah[a] = h;
            *(uint4*)&Al[a] = l;
        }
    }
    __syncthreads();

    f32x4 acc[4];
    #pragma unroll
    for (int mf = 0; mf < 4; mf++) { f32x4 z = {0.f,0.f,0.f,0.f}; acc[mf] = z; }

    for (int ky = 0; ky < 3; ky++) {
        for (int kx = 0; kx < 3; kx++) {
            int kk = ky*3 + kx;
            int xib = (kx & 1)*17 + (kx >> 1);
            s16x8 ah[4], al[4];
            #pragma unroll
            for (int mf = 0; mf < 4; mf++) {
                int hy = 2*mf + ky;
                int a = ((ks*9 + hy)*34 + xib + m)*8;
                ah[mf] = *(const s16x8*)&Ah[a];
                al[mf] = *(const s16x8*)&Al[a];
            }
            const unsigned short* wb = W2F + kk*4096;
            s16x8 bh  = *(const s16x8*)(wb + wv*512 + lane*8);
            s16x8 blo = *(const s16x8*)(wb + 2048 + wv*512 + lane*8);
            #pragma unroll
            for (int mf = 0; mf < 4; mf++) {
                acc[mf] = __builtin_amdgcn_mfma_f32_16x16x32_bf16(ah[mf], bh,  acc[mf], 0, 0, 0);
                acc[mf] = __builtin_amdgcn_mfma_f32_16x16x32_bf16(ah[mf], blo, acc[mf], 0, 0, 0);
                acc[mf] = __builtin_amdgcn_mfma_f32_16x16x32_bf16(al[mf], bh,  acc[mf], 0, 0, 0);
            }
        }
    }

    const int co = wv*16 + m;
    const float bv = W[19328 + co];
    #pragma unroll
    for (int mf = 0; mf < 4; mf++) {
        int y = OY + mf;
        #pragma unroll
        for (int r = 0; r < 4; r++) {
            int xo = OX + ks*4 + r;
            float rv = fmaxf(acc[mf][r] + bv, 0.f);
            unsigned short h = f2bf(rv);
            unsigned short l = f2bf(rv - bf2f(h));
            size_t a = ((size_t)(bl*16384 + y*128 + xo))*64 + co;
            A2H[a] = h;
            A2L[a] = l;
        }
    }
}

__global__ __launch_bounds__(256, 2) void conv3mm_k(
    const unsigned short* __restrict__ A2H, const unsigned short* __restrict__ A2L,
    const unsigned short* __restrict__ W3F, const float* __restrict__ bias,
    unsigned* __restrict__ A3P)
{
    const int tid  = threadIdx.x;
    const int lane = tid & 63;
    const int w    = tid >> 6;
    const int bl   = blockIdx.x >> 6;
    const int y    = blockIdx.x & 63;
    const int m    = lane & 15;
    const int ks   = lane >> 4;

    f32x4 acc[4][2];
    #pragma unroll
    for (int mf = 0; mf < 4; mf++)
        #pragma unroll
        for (int nfl = 0; nfl < 2; nfl++) {
            f32x4 z = {0.f, 0.f, 0.f, 0.f};
            acc[mf][nfl] = z;
        }

    const size_t ibase = (size_t)bl * 16384 * 64;

    for (int ky = 0; ky < 3; ky++) {
        int iy = 2*y + ky - 1;
        if ((unsigned)iy >= 128u) continue;
        for (int kx = 0; kx < 3; kx++) {
            int kk = ky*3 + kx;
            #pragma unroll
            for (int cig = 0; cig < 2; cig++) {
                s16x8 ah[4], al[4];
                #pragma unroll
                for (int mf = 0; mf < 4; mf++) {
                    int xo = mf*16 + m;
                    int ix = 2*xo + kx - 1;
                    bool v = ix >= 0;
                    int ixc = v ? ix : 0;
                    size_t a = ibase + ((size_t)iy*128 + ixc)*64 + cig*32 + ks*8;
                    s16x8 zh = {0,0,0,0,0,0,0,0};
                    s16x8 th = *(const s16x8*)(A2H + a);
                    s16x8 tl = *(const s16x8*)(A2L + a);
                    ah[mf] = v ? th : zh;
                    al[mf] = v ? tl : zh;
                }
                const unsigned short* wb = W3F + (kk*2 + cig)*8192;
                #pragma unroll
                for (int nfl = 0; nfl < 2; nfl++) {
                    int nfg = w*2 + nfl;
                    s16x8 bh  = *(const s16x8*)(wb + nfg*512 + lane*8);
                    s16x8 blo = *(const s16x8*)(wb + 4096 + nfg*512 + lane*8);
                    #pragma unroll
                    for (int mf = 0; mf < 4; mf++) {
                        acc[mf][nfl] = __builtin_amdgcn_mfma_f32_16x16x32_bf16(ah[mf], bh,  acc[mf][nfl], 0, 0, 0);
                        acc[mf][nfl] = __builtin_amdgcn_mfma_f32_16x16x32_bf16(ah[mf], blo, acc[mf][nfl], 0, 0, 0);
                        acc[mf][nfl] = __builtin_amdgcn_mfma_f32_16x16x32_bf16(al[mf], bh,  acc[mf][nfl], 0, 0, 0);
                    }
                }
            }
        }
    }

    const size_t obase = ((size_t)(bl*64 + y))*64*128;
    #pragma unroll
    for (int nfl = 0; nfl < 2; nfl++) {
        int co = (w*2 + nfl)*16 + m;
        float bv = bias[co];
        #pragma unroll
        for (int mf = 0; mf < 4; mf++) {
            #pragma unroll
            for (int r = 0; r < 4; r++) {
                float rv = fmaxf(acc[mf][nfl][r] + bv, 0.f);
                unsigned short h = f2bf(rv);
                unsigned short l = f2bf(rv - bf2f(h));
                int xo = mf*16 + ks*4 + r;
                A3P[obase + (size_t)xo*128 + co] = (unsigned)h | ((unsigned)l << 16);
            }
        }
    }
}

// ---------------- MFMA head (BOTH heads, 16-wave blocks): conv3x3+ReLU+1x1 ----------
// ONE row per block, grid 512. 1024 threads = 16 waves; wave w owns co group nfg=w
// (16 co) for BOTH heads: acc0[4] + acc1[4] = 32 VGPR, statically indexed.
// A3P staged once per block (FETCH halved vs split-head); round-14 clean LDS pattern.
__global__ __launch_bounds__(1024, 4) void headmm_k(
    const unsigned* __restrict__ A3P, const unsigned short* __restrict__ WF,
    const float* __restrict__ db1, const float* __restrict__ dw2, const float* __restrict__ db2,
    const float* __restrict__ bb1, const float* __restrict__ bw2, const float* __restrict__ bb2,
    float* __restrict__ SC, float* __restrict__ BF, int b0)
{
    __shared__ __attribute__((aligned(16))) unsigned short Ah[8704];  // [4kgrp][4row(3 used)][68x'][8ci]
    __shared__ __attribute__((aligned(16))) unsigned short Al[8704];
    __shared__ float red[16][4][64];                // 16 KB

    const int tid  = threadIdx.x;                   // 0..1023
    const int lane = tid & 63;
    const int w    = tid >> 6;                      // 0..15 : co group of 16 (nfg = w)
    const int imgl = blockIdx.x >> 6;               // chunk-local image
    const int y    = blockIdx.x & 63;               // output row

    f32x4 acc0[4], acc1[4];                         // [mf] for head 0 / head 1
    #pragma unroll
    for (int mf = 0; mf < 4; mf++) {
        f32x4 z = {0.f, 0.f, 0.f, 0.f};
        acc0[mf] = z;
        acc1[mf] = z;
    }

    const unsigned* abase = A3P + (size_t)imgl * 64 * 64 * 128;

    // staging task t in [0,792): kgrp = t&3, xi = (t>>2)%66, row = (t>>2)/66 (0..2)
    uint4 pva, pvb;
    #define HM_ISSUE(CIG)                                                          \
        {                                                                          \
            uint4 z4 = {0u,0u,0u,0u};                                              \
            pva = z4; pvb = z4;                                                    \
            if (tid < 792) {                                                       \
                int kgrp = tid & 3; int q = tid >> 2;                              \
                int xi = q % 66;  int row = q / 66;                                \
                int gr = y + row - 1, gx = xi - 1;                                 \
                if (((unsigned)gr < 64u) && ((unsigned)gx < 64u)) {                \
                    const uint4* p = (const uint4*)(abase + ((size_t)gr*64 + gx)*128 \
                                                    + (CIG)*32 + kgrp*8);          \
                    pva = p[0]; pvb = p[1];                                        \
                }                                                                  \
            }                                                                      \
        }

    HM_ISSUE(0);
    for (int cig = 0; cig < 4; cig++) {
        __syncthreads();                            // prior compute's LDS reads done
        if (tid < 792) {
            int kgrp = tid & 3; int q = tid >> 2;
            int xi = q % 66;  int row = q / 66;
            int a = ((kgrp*4 + row)*68 + xi)*8;
            uint4 va = pva, vb = pvb;
            uint4 h, l;
            h.x = (va.x & 0xffffu) | (va.y << 16);
            h.y = (va.z & 0xffffu) | (va.w << 16);
            h.z = (vb.x & 0xffffu) | (vb.y << 16);
            h.w = (vb.z & 0xffffu) | (vb.w << 16);
            l.x = (va.x >> 16) | (va.y & 0xffff0000u);
            l.y = (va.z >> 16) | (va.w & 0xffff0000u);
            l.z = (vb.x >> 16) | (vb.y & 0xffff0000u);
            l.w = (vb.z >> 16) | (vb.w & 0xffff0000u);
            *(uint4*)&Ah[a] = h;
            *(uint4*)&Al[a] = l;
        }
        if (cig < 3) { HM_ISSUE(cig + 1); }         // loads fly across the barrier
        __syncthreads();
        __builtin_amdgcn_s_setprio(1);
        #pragma unroll 1
        for (int kk = 0; kk < 9; kk++) {
            int ky = kk / 3, kx = kk - 3*(kk/3);
            s16x8 ah[4], al[4];
            #pragma unroll
            for (int mf = 0; mf < 4; mf++) {
                int xq = (lane & 15) + 16*mf + kx;
                int a = (((lane >> 4)*4 + ky)*68 + xq)*8;
                ah[mf] = *(const s16x8*)&Ah[a];
                al[mf] = *(const s16x8*)&Al[a];
            }
            const unsigned short* wk0 = WF + kk*65536 + cig*16384;
            const unsigned short* wk1 = wk0 + 589824;
            s16x8 b0h = *(const s16x8*)(wk0 + w*512 + lane*8);
            s16x8 b0l = *(const s16x8*)(wk0 + 8192 + w*512 + lane*8);
            s16x8 b1h = *(const s16x8*)(wk1 + w*512 + lane*8);
            s16x8 b1l = *(const s16x8*)(wk1 + 8192 + w*512 + lane*8);
            #pragma unroll
            for (int mf = 0; mf < 4; mf++) {
                acc0[mf] = __builtin_amdgcn_mfma_f32_16x16x32_bf16(ah[mf], b0h, acc0[mf], 0, 0, 0);
                acc0[mf] = __builtin_amdgcn_mfma_f32_16x16x32_bf16(ah[mf], b0l, acc0[mf], 0, 0, 0);
                acc0[mf] = __builtin_amdgcn_mfma_f32_16x16x32_bf16(al[mf], b0h, acc0[mf], 0, 0, 0);
                acc1[mf] = __builtin_amdgcn_mfma_f32_16x16x32_bf16(ah[mf], b1h, acc1[mf], 0, 0, 0);
                acc1[mf] = __builtin_amdgcn_mfma_f32_16x16x32_bf16(ah[mf], b1l, acc1[mf], 0, 0, 0);
                acc1[mf] = __builtin_amdgcn_mfma_f32_16x16x32_bf16(al[mf], b1h, acc1[mf], 0, 0, 0);
            }
        }
        __builtin_amdgcn_s_setprio(0);
    }
    #undef HM_ISSUE

    // ---- head 0 (det, NOUT=1): bias+ReLU, 1x1 partial, 16-wave reduction ----
    {
        float bv = db1[(lane & 15) + w*16];
        #pragma unroll
        for (int mf = 0; mf < 4; mf++)
            #pragma unroll
            for (int r = 0; r < 4; r++)
                acc0[mf][r] = fmaxf(acc0[mf][r] + bv, 0.f);
        float wq = dw2[(lane & 15) + w*16];
        #pragma unroll
        for (int mf = 0; mf < 4; mf++) {
            #pragma unroll
            for (int r = 0; r < 4; r++) {
                float v = acc0[mf][r] * wq;
                v += __shfl_xor(v, 1);
                v += __shfl_xor(v, 2);
                v += __shfl_xor(v, 4);
                v += __shfl_xor(v, 8);
                if ((lane & 15) == 0)
                    red[w][0][mf*16 + (lane >> 4)*4 + r] = v;
            }
        }
        __syncthreads();
        if (tid < 64) {
            float v = db2[0];
            #pragma unroll
            for (int ww = 0; ww < 16; ww++) v += red[ww][0][tid];
            SC[((size_t)(b0 + imgl))*4096 + y*64 + tid] = v;   // raw logit
        }
        __syncthreads();
    }
    // ---- head 1 (bbox, NOUT=4) ----
    {
        float bv = bb1[(lane & 15) + w*16];
        #pragma unroll
        for (int mf = 0; mf < 4; mf++)
            #pragma unroll
            for (int r = 0; r < 4; r++)
                acc1[mf][r] = fmaxf(acc1[mf][r] + bv, 0.f);
        for (int p = 0; p < 4; p++) {
            float wq = bw2[p*256 + (lane & 15) + w*16];
            #pragma unroll
            for (int mf = 0; mf < 4; mf++) {
                #pragma unroll
                for (int r = 0; r < 4; r++) {
                    float v = acc1[mf][r] * wq;
                    v += __shfl_xor(v, 1);
                    v += __shfl_xor(v, 2);
                    v += __shfl_xor(v, 4);
                    v += __shfl_xor(v, 8);
                    if ((lane & 15) == 0)
                        red[w][p][mf*16 + (lane >> 4)*4 + r] = v;
                }
            }
        }
        __syncthreads();
        if (tid < 256) {
            int p = tid >> 6; int px = tid & 63;
            float v = bb2[p];
            #pragma unroll
            for (int ww = 0; ww < 16; ww++) v += red[ww][p][px];
            BF[((size_t)((b0 + imgl)*4 + p))*4096 + y*64 + px] = v;  // raw logit
        }
    }
}

__global__ __launch_bounds__(256) void topk_k(
    const float* __restrict__ scores, const float* __restrict__ bflat,
    float* __restrict__ outp)
{
    __shared__ float sv[4096];
    __shared__ float rv[256];
    __shared__ int   ri[256];
    __shared__ float kv[8];
    __shared__ int   kidx[8];
    int b = blockIdx.x, t = threadIdx.x;
    for (int i = t; i < 4096; i += 256) sv[i] = scores[b*4096 + i];
    __syncthreads();
    for (int k = 0; k < 8; k++) {
        float bv = -INFINITY; int bi = 0x7fffffff;
        for (int i = t; i < 4096; i += 256) {
            float v = sv[i];
            if (v > bv || (v == bv && i < bi)) { bv = v; bi = i; }
        }
        rv[t] = bv; ri[t] = bi;
        __syncthreads();
        for (int s = 128; s > 0; s >>= 1) {
            if (t < s) {
                float v2 = rv[t+s]; int i2 = ri[t+s];
                if (v2 > rv[t] || (v2 == rv[t] && i2 < ri[t])) { rv[t] = v2; ri[t] = i2; }
            }
            __syncthreads();
        }
        if (t == 0) { kv[k] = rv[0]; kidx[k] = ri[0]; sv[ri[0]] = -INFINITY; }
        __syncthreads();
    }
    if (t < 32) {
        int k = t >> 2, c = t & 3;
        int idx = kidx[k];
        float s  = 1.f / (1.f + expf(-kv[k]));
        float lg = bflat[((size_t)(b*4 + c))*4096 + idx];
        float box = 512.f / (1.f + expf(-lg));
        outp[(b*8 + k)*4 + c] = (s > 0.5f) ? box : 0.f;
    }
}

extern "C" void kernel_launch(void* const* d_in, const int* in_sizes, int n_in,
                              void* d_out, int out_size, void* d_ws, size_t ws_size,
                              hipStream_t stream)
{
    const float* x   = (const float*)d_in[0];
    const float* w1  = (const float*)d_in[1];
    const float* b1  = (const float*)d_in[2];
    const float* g1  = (const float*)d_in[3];
    const float* be1 = (const float*)d_in[4];
    const float* m1  = (const float*)d_in[5];
    const float* v1  = (const float*)d_in[6];
    const float* w2  = (const float*)d_in[7];
    const float* b2  = (const float*)d_in[8];
    const float* g2  = (const float*)d_in[9];
    const float* be2 = (const float*)d_in[10];
    const float* m2  = (const float*)d_in[11];
    const float* v2  = (const float*)d_in[12];
    const float* w3  = (const float*)d_in[13];
    const float* b3  = (const float*)d_in[14];
    const float* g3  = (const float*)d_in[15];
    const float* be3 = (const float*)d_in[16];
    const float* m3  = (const float*)d_in[17];
    const float* v3  = (const float*)d_in[18];
    const float* dw1 = (const float*)d_in[19];
    const float* db1 = (const float*)d_in[20];
    const float* dw2 = (const float*)d_in[21];
    const float* db2 = (const float*)d_in[22];
    const float* bw1 = (const float*)d_in[23];
    const float* bb1 = (const float*)d_in[24];
    const float* bw2 = (const float*)d_in[25];
    const float* bb2 = (const float*)d_in[26];

    char*  wsb = (char*)d_ws;
    float*          W   = (float*)wsb;
    unsigned short* WF  = (unsigned short*)(wsb + 372992);
    unsigned short* W3F = (unsigned short*)(wsb + 2732288);
    float*          SC  = (float*)(wsb + 3027200);
    float*          BF  = (float*)(wsb + 3551488);
    unsigned short* A2H = (unsigned short*)(wsb + 5648640);
    unsigned short* A2L = (unsigned short*)(wsb + 22425856);
    unsigned*       A3P = (unsigned*)(wsb + 39203072);
    unsigned short* W2F = (unsigned short*)(wsb + 55980288);
    float* out = (float*)d_out;

    prep_k <<<365, 256, 0, stream>>>(w1,b1,g1,be1,m1,v1, w2,b2,g2,be2,m2,v2,
                                     w3,b3,g3,be3,m3,v3, W);
    prep2_k<<<4608, 256, 0, stream>>>(dw1, bw1, WF);
    prep3_k<<<576, 256, 0, stream>>>(w3, g3, v3, W3F);
    prep4_k<<<144, 256, 0, stream>>>(w2, g2, v2, W2F);

    for (int c = 0; c < 4; c++) {
        conv12mm_k<<<2048, 256, 0, stream>>>(x, W, W2F, A2H, A2L, c*8);
        conv3mm_k <<<512, 256, 0, stream>>>(A2H, A2L, W3F, W + 93120, A3P);
        headmm_k  <<<512, 1024, 0, stream>>>(A3P, WF, db1, dw2, db2, bb1, bw2, bb2,
                                             SC, BF, c*8);
    }
    topk_k<<<32, 256, 0, stream>>>(SC, BF, out);
}

// Round 16
// 748.629 us; speedup vs baseline: 1.0728x; 1.0728x over previous
//
#include <hip/hip_runtime.h>
#include <math.h>

#define EPSBN 1e-5f

typedef __attribute__((ext_vector_type(4))) float f32x4;
typedef __attribute__((ext_vector_type(8))) short s16x8;

__device__ __forceinline__ unsigned short f2bf(float f) {
    unsigned u = __builtin_bit_cast(unsigned, f);
    u = (u + 0x7fffu + ((u >> 16) & 1u)) >> 16;
    return (unsigned short)u;
}
__device__ __forceinline__ float bf2f(unsigned short s) {
    unsigned u = ((unsigned)s) << 16;
    return __builtin_bit_cast(float, u);
}

// ---------------- workspace layout (BYTE offsets), peak 56,054,016 B ----------------
// W @0 | WF @372,992 | W3F @2,732,288 | SC @3,027,200 | BF @3,551,488
// A2H @5,648,640 | A2L @22,425,856 | A3P @39,203,072 | W2F @55,980,288

__global__ __launch_bounds__(256) void prep_k(
    const float* __restrict__ w1, const float* __restrict__ b1, const float* __restrict__ g1,
    const float* __restrict__ be1, const float* __restrict__ m1, const float* __restrict__ v1,
    const float* __restrict__ w2, const float* __restrict__ b2, const float* __restrict__ g2,
    const float* __restrict__ be2, const float* __restrict__ m2, const float* __restrict__ v2,
    const float* __restrict__ w3, const float* __restrict__ b3, const float* __restrict__ g3,
    const float* __restrict__ be3, const float* __restrict__ m3, const float* __restrict__ v3,
    float* __restrict__ W)
{
    int i = blockIdx.x * 256 + threadIdx.x;
    if (i < 864) {
        int co = i & 31; int r = i >> 5; int ci = r % 3; int kk = r / 3;
        float A = g1[co] * rsqrtf(v1[co] + EPSBN);
        W[i] = w1[(co*3 + ci)*9 + kk] * A;
    } else if (i < 896) {
        int co = i - 864;
        float A = g1[co] * rsqrtf(v1[co] + EPSBN);
        W[i] = (b1[co] - m1[co]) * A + be1[co];
    } else if (i >= 19328 && i < 19392) {
        int co = i - 19328;
        float A = g2[co] * rsqrtf(v2[co] + EPSBN);
        W[i] = (b2[co] - m2[co]) * A + be2[co];
    } else if (i >= 93120 && i < 93248) {
        int co = i - 93120;
        float A = g3[co] * rsqrtf(v3[co] + EPSBN);
        W[i] = (b3[co] - m3[co]) * A + be3[co];
    }
}

__global__ __launch_bounds__(256) void prep2_k(
    const float* __restrict__ dw1, const float* __restrict__ bw1,
    unsigned short* __restrict__ WF)
{
    int i = blockIdx.x * 256 + threadIdx.x;
    if (i >= 1179648) return;
    int head = i / 589824;
    int r    = i - head * 589824;
    int kk   = r >> 16;
    int r2   = r & 65535;
    int cig  = r2 >> 14;
    int pl   = (r2 >> 13) & 1;
    int nf   = (r2 >> 9) & 15;
    int lane = (r2 >> 3) & 63;
    int j    = r2 & 7;
    int ci = cig*32 + (lane >> 4)*8 + j;
    int co = (lane & 15) + nf*16;
    const float* src = head ? bw1 : dw1;
    float w = src[(co*128 + ci)*9 + kk];
    unsigned short h = f2bf(w);
    WF[i] = pl ? f2bf(w - bf2f(h)) : h;
}

__global__ __launch_bounds__(256) void prep3_k(
    const float* __restrict__ w3, const float* __restrict__ g3, const float* __restrict__ v3,
    unsigned short* __restrict__ W3F)
{
    int i = blockIdx.x * 256 + threadIdx.x;
    if (i >= 147456) return;
    int kk = i >> 14;
    int r  = i & 16383;
    int cig = r >> 13;
    int pl  = (r >> 12) & 1;
    int nf  = (r >> 9) & 7;
    int lane = (r >> 3) & 63;
    int j   = r & 7;
    int ci = cig*32 + (lane >> 4)*8 + j;
    int co = nf*16 + (lane & 15);
    float A = g3[co] * rsqrtf(v3[co] + EPSBN);
    float w = w3[(co*64 + ci)*9 + kk] * A;
    unsigned short h = f2bf(w);
    W3F[i] = pl ? f2bf(w - bf2f(h)) : h;
}

__global__ __launch_bounds__(256) void prep4_k(
    const float* __restrict__ w2, const float* __restrict__ g2, const float* __restrict__ v2,
    unsigned short* __restrict__ W2F)
{
    int i = blockIdx.x * 256 + threadIdx.x;
    if (i >= 36864) return;
    int kk = i >> 12;
    int r  = i & 4095;
    int pl  = r >> 11;
    int nfg = (r >> 9) & 3;
    int lane = (r >> 3) & 63;
    int j   = r & 7;
    int ci = (lane >> 4)*8 + j;
    int co = nfg*16 + (lane & 15);
    float A = g2[co] * rsqrtf(v2[co] + EPSBN);
    float w = w2[(co*32 + ci)*9 + kk] * A;
    unsigned short h = f2bf(w);
    W2F[i] = pl ? f2bf(w - bf2f(h)) : h;
}

// ---------------- fused conv1(VALU)+conv2(MFMA), tile 16x2 out2, grid 4096/chunk ----
__global__ __launch_bounds__(256, 4) void conv12mm_k(
    const float* __restrict__ x, const float* __restrict__ W,
    const unsigned short* __restrict__ W2F,
    unsigned short* __restrict__ A2H, unsigned short* __restrict__ A2L, int b0)
{
    __shared__ __attribute__((aligned(16))) unsigned short Ah[5440]; // [4kg][5hy][34xi][8]
    __shared__ __attribute__((aligned(16))) unsigned short Al[5440];

    const int tid  = threadIdx.x;
    const int lane = tid & 63;
    const int wv   = tid >> 6;                      // co group 0..3
    const int m    = lane & 15;
    const int ks   = lane >> 4;

    const int bl   = blockIdx.x >> 9;               // chunk-local image
    const int tile = blockIdx.x & 511;
    const int OY = (tile >> 3) * 2;                 // out2 row base (64 row-tiles)
    const int OX = (tile & 7) * 16;                 // out2 col base
    const int base1y = 2*OY - 1, base1x = 2*OX - 1;

    const float* xb = x + (size_t)(b0 + bl) * 3 * 262144;

    // ---- conv1: 5x33 = 165 halo px, all 32 couts, exact f32 -> hi/lo planes ----
    if (tid < 165) {
        int row = tid / 33, lx = tid - row*33;
        int y1 = base1y + row, x1 = base1x + lx;
        float c1[32];
        #pragma unroll
        for (int c = 0; c < 32; c++) c1[c] = 0.f;
        if (((unsigned)y1 < 256u) && ((unsigned)x1 < 256u)) {
            #pragma unroll
            for (int ky = 0; ky < 3; ky++) {
                int xy = 2*y1 + ky - 1;
                if ((unsigned)xy < 512u) {
                    #pragma unroll
                    for (int kx = 0; kx < 3; kx++) {
                        int xx = 2*x1 + kx - 1;
                        if ((unsigned)xx < 512u) {
                            int kk = ky*3 + kx;
                            #pragma unroll
                            for (int ci = 0; ci < 3; ci++) {
                                float v = xb[(size_t)ci*262144 + xy*512 + xx];
                                const float4* w4 = (const float4*)(W + (kk*3+ci)*32);
                                float4 wa = w4[0], wb = w4[1], wc = w4[2], wd = w4[3];
                                float4 we = w4[4], wf = w4[5], wg = w4[6], wh = w4[7];
                                c1[0]  = fmaf(v, wa.x, c1[0]);  c1[1]  = fmaf(v, wa.y, c1[1]);
                                c1[2]  = fmaf(v, wa.z, c1[2]);  c1[3]  = fmaf(v, wa.w, c1[3]);
                                c1[4]  = fmaf(v, wb.x, c1[4]);  c1[5]  = fmaf(v, wb.y, c1[5]);
                                c1[6]  = fmaf(v, wb.z, c1[6]);  c1[7]  = fmaf(v, wb.w, c1[7]);
                                c1[8]  = fmaf(v, wc.x, c1[8]);  c1[9]  = fmaf(v, wc.y, c1[9]);
                                c1[10] = fmaf(v, wc.z, c1[10]); c1[11] = fmaf(v, wc.w, c1[11]);
                                c1[12] = fmaf(v, wd.x, c1[12]); c1[13] = fmaf(v, wd.y, c1[13]);
                                c1[14] = fmaf(v, wd.z, c1[14]); c1[15] = fmaf(v, wd.w, c1[15]);
                                c1[16] = fmaf(v, we.x, c1[16]); c1[17] = fmaf(v, we.y, c1[17]);
                                c1[18] = fmaf(v, we.z, c1[18]); c1[19] = fmaf(v, we.w, c1[19]);
                                c1[20] = fmaf(v, wf.x, c1[20]); c1[21] = fmaf(v, wf.y, c1[21]);
                                c1[22] = fmaf(v, wf.z, c1[22]); c1[23] = fmaf(v, wf.w, c1[23]);
                                c1[24] = fmaf(v, wg.x, c1[24]); c1[25] = fmaf(v, wg.y, c1[25]);
                                c1[26] = fmaf(v, wg.z, c1[26]); c1[27] = fmaf(v, wg.w, c1[27]);
                                c1[28] = fmaf(v, wh.x, c1[28]); c1[29] = fmaf(v, wh.y, c1[29]);
                                c1[30] = fmaf(v, wh.z, c1[30]); c1[31] = fmaf(v, wh.w, c1[31]);
                            }
                        }
                    }
                }
            }
            #pragma unroll
            for (int c = 0; c < 32; c++)
                c1[c] = fmaxf(c1[c] + W[864 + c], 0.f);
        }
        int xi = (lx & 1)*17 + (lx >> 1);           // column interleave (0..32)
        #pragma unroll
        for (int kg = 0; kg < 4; kg++) {
            uint4 h, l;
            unsigned hw[4], lw[4];
            #pragma unroll
            for (int q = 0; q < 4; q++) {
                float r0 = c1[kg*8 + 2*q], r1 = c1[kg*8 + 2*q + 1];
                unsigned short h0 = f2bf(r0), h1 = f2bf(r1);
                unsigned short l0 = f2bf(r0 - bf2f(h0)), l1 = f2bf(r1 - bf2f(h1));
                hw[q] = (unsigned)h0 | ((unsigned)h1 << 16);
                lw[q] = (unsigned)l0 | ((unsigned)l1 << 16);
            }
            h.x = hw[0]; h.y = hw[1]; h.z = hw[2]; h.w = hw[3];
            l.x = lw[0]; l.y = lw[1]; l.z = lw[2]; l.w = lw[3];
            int a = ((kg*5 + row)*34 + xi)*8;
            *(uint4*)&Ah[a] = h;
            *(uint4*)&Al[a] = l;
        }
    }
    __syncthreads();

    // ---- conv2: split-bf16 MFMA, M=32px (2 mf), N=16co per wave, K=288 ----
    f32x4 acc[2];
    #pragma unroll
    for (int mf = 0; mf < 2; mf++) { f32x4 z = {0.f,0.f,0.f,0.f}; acc[mf] = z; }

    for (int ky = 0; ky < 3; ky++) {
        for (int kx = 0; kx < 3; kx++) {
            int kk = ky*3 + kx;
            int xib = (kx & 1)*17 + (kx >> 1);
            s16x8 ah[2], al[2];
            #pragma unroll
            for (int mf = 0; mf < 2; mf++) {
                int hy = 2*mf + ky;                 // 0..4
                int a = ((ks*5 + hy)*34 + xib + m)*8;
                ah[mf] = *(const s16x8*)&Ah[a];
                al[mf] = *(const s16x8*)&Al[a];
            }
            const unsigned short* wb = W2F + kk*4096;
            s16x8 bh  = *(const s16x8*)(wb + wv*512 + lane*8);
            s16x8 blo = *(const s16x8*)(wb + 2048 + wv*512 + lane*8);
            #pragma unroll
            for (int mf = 0; mf < 2; mf++) {
                acc[mf] = __builtin_amdgcn_mfma_f32_16x16x32_bf16(ah[mf], bh,  acc[mf], 0, 0, 0);
                acc[mf] = __builtin_amdgcn_mfma_f32_16x16x32_bf16(ah[mf], blo, acc[mf], 0, 0, 0);
                acc[mf] = __builtin_amdgcn_mfma_f32_16x16x32_bf16(al[mf], bh,  acc[mf], 0, 0, 0);
            }
        }
    }

    // ---- epilogue: +bias, ReLU, split hi/lo -> A2 NHWC ----
    const int co = wv*16 + m;
    const float bv = W[19328 + co];
    #pragma unroll
    for (int mf = 0; mf < 2; mf++) {
        int y = OY + mf;
        #pragma unroll
        for (int r = 0; r < 4; r++) {
            int xo = OX + ks*4 + r;
            float rv = fmaxf(acc[mf][r] + bv, 0.f);
            unsigned short h = f2bf(rv);
            unsigned short l = f2bf(rv - bf2f(h));
            size_t a = ((size_t)(bl*16384 + y*128 + xo))*64 + co;
            A2H[a] = h;
            A2L[a] = l;
        }
    }
}

// ---------------- conv3 MFMA: x-half per block, grid 1024/chunk, 4 blocks/CU --------
__global__ __launch_bounds__(256, 4) void conv3mm_k(
    const unsigned short* __restrict__ A2H, const unsigned short* __restrict__ A2L,
    const unsigned short* __restrict__ W3F, const float* __restrict__ bias,
    unsigned* __restrict__ A3P)
{
    const int tid  = threadIdx.x;
    const int lane = tid & 63;
    const int w    = tid >> 6;                      // co quarter 0..3
    const int xh   = blockIdx.x & 1;                // x half (0/1)
    const int y    = (blockIdx.x >> 1) & 63;        // out row
    const int bl   = blockIdx.x >> 7;               // chunk-local image
    const int m    = lane & 15;
    const int ks   = lane >> 4;

    f32x4 acc[2][2];
    #pragma unroll
    for (int mf = 0; mf < 2; mf++)
        #pragma unroll
        for (int nfl = 0; nfl < 2; nfl++) {
            f32x4 z = {0.f, 0.f, 0.f, 0.f};
            acc[mf][nfl] = z;
        }

    const size_t ibase = (size_t)bl * 16384 * 64;

    for (int ky = 0; ky < 3; ky++) {
        int iy = 2*y + ky - 1;
        if ((unsigned)iy >= 128u) continue;
        for (int kx = 0; kx < 3; kx++) {
            int kk = ky*3 + kx;
            #pragma unroll
            for (int cig = 0; cig < 2; cig++) {
                s16x8 ah[2], al[2];
                #pragma unroll
                for (int mf = 0; mf < 2; mf++) {
                    int xo = xh*32 + mf*16 + m;
                    int ix = 2*xo + kx - 1;
                    bool v = ix >= 0;
                    int ixc = v ? ix : 0;
                    size_t a = ibase + ((size_t)iy*128 + ixc)*64 + cig*32 + ks*8;
                    s16x8 zh = {0,0,0,0,0,0,0,0};
                    s16x8 th = *(const s16x8*)(A2H + a);
                    s16x8 tl = *(const s16x8*)(A2L + a);
                    ah[mf] = v ? th : zh;
                    al[mf] = v ? tl : zh;
                }
                const unsigned short* wb = W3F + (kk*2 + cig)*8192;
                #pragma unroll
                for (int nfl = 0; nfl < 2; nfl++) {
                    int nfg = w*2 + nfl;
                    s16x8 bh  = *(const s16x8*)(wb + nfg*512 + lane*8);
                    s16x8 blo = *(const s16x8*)(wb + 4096 + nfg*512 + lane*8);
                    #pragma unroll
                    for (int mf = 0; mf < 2; mf++) {
                        acc[mf][nfl] = __builtin_amdgcn_mfma_f32_16x16x32_bf16(ah[mf], bh,  acc[mf][nfl], 0, 0, 0);
                        acc[mf][nfl] = __builtin_amdgcn_mfma_f32_16x16x32_bf16(ah[mf], blo, acc[mf][nfl], 0, 0, 0);
                        acc[mf][nfl] = __builtin_amdgcn_mfma_f32_16x16x32_bf16(al[mf], bh,  acc[mf][nfl], 0, 0, 0);
                    }
                }
            }
        }
    }

    const size_t obase = ((size_t)(bl*64 + y))*64*128;
    #pragma unroll
    for (int nfl = 0; nfl < 2; nfl++) {
        int co = (w*2 + nfl)*16 + m;
        float bv = bias[co];
        #pragma unroll
        for (int mf = 0; mf < 2; mf++) {
            #pragma unroll
            for (int r = 0; r < 4; r++) {
                float rv = fmaxf(acc[mf][nfl][r] + bv, 0.f);
                unsigned short h = f2bf(rv);
                unsigned short l = f2bf(rv - bf2f(h));
                int xo = xh*32 + mf*16 + ks*4 + r;
                A3P[obase + (size_t)xo*128 + co] = (unsigned)h | ((unsigned)l << 16);
            }
        }
    }
}

// ---------------- MFMA head (round-14 exact: split heads, grid (512,2)) -------------
__global__ __launch_bounds__(512, 2) void headmm_k(
    const unsigned* __restrict__ A3P, const unsigned short* __restrict__ WF,
    const float* __restrict__ db1, const float* __restrict__ dw2, const float* __restrict__ db2,
    const float* __restrict__ bb1, const float* __restrict__ bw2, const float* __restrict__ bb2,
    float* __restrict__ SC, float* __restrict__ BF, int b0)
{
    __shared__ __attribute__((aligned(16))) unsigned short Ah[8704];
    __shared__ __attribute__((aligned(16))) unsigned short Al[8704];
    __shared__ float red[8][4][64];

    const int tid  = threadIdx.x;
    const int lane = tid & 63;
    const int w    = tid >> 6;
    const int head = blockIdx.y;
    const int imgl = blockIdx.x >> 6;
    const int y    = blockIdx.x & 63;

    f32x4 acc[4][2];
    #pragma unroll
    for (int mf = 0; mf < 4; mf++)
        #pragma unroll
        for (int nf = 0; nf < 2; nf++) {
            f32x4 z = {0.f, 0.f, 0.f, 0.f};
            acc[mf][nf] = z;
        }

    const unsigned* abase = A3P + (size_t)imgl * 64 * 64 * 128;
    const unsigned short* WFh = WF + head * 589824;

    uint4 pva[2], pvb[2];
    #define HM_ISSUE(CIG)                                                          \
        _Pragma("unroll")                                                          \
        for (int it = 0; it < 2; it++) {                                           \
            int t = tid + it*512;                                                  \
            uint4 z4 = {0u,0u,0u,0u};                                              \
            pva[it] = z4; pvb[it] = z4;                                            \
            if (t < 792) {                                                         \
                int kgrp = t & 3; int q = t >> 2;                                  \
                int xi = q % 66;  int row = q / 66;                                \
                int gr = y + row - 1, gx = xi - 1;                                 \
                if (((unsigned)gr < 64u) && ((unsigned)gx < 64u)) {                \
                    const uint4* p = (const uint4*)(abase + ((size_t)gr*64 + gx)*128 \
                                                    + (CIG)*32 + kgrp*8);          \
                    pva[it] = p[0]; pvb[it] = p[1];                                \
                }                                                                  \
            }                                                                      \
        }

    HM_ISSUE(0);
    for (int cig = 0; cig < 4; cig++) {
        __syncthreads();
        #pragma unroll
        for (int it = 0; it < 2; it++) {
            int t = tid + it*512;
            if (t < 792) {
                int kgrp = t & 3; int q = t >> 2;
                int xi = q % 66;  int row = q / 66;
                int a = ((kgrp*4 + row)*68 + xi)*8;
                uint4 va = pva[it], vb = pvb[it];
                uint4 h, l;
                h.x = (va.x & 0xffffu) | (va.y << 16);
                h.y = (va.z & 0xffffu) | (va.w << 16);
                h.z = (vb.x & 0xffffu) | (vb.y << 16);
                h.w = (vb.z & 0xffffu) | (vb.w << 16);
                l.x = (va.x >> 16) | (va.y & 0xffff0000u);
                l.y = (va.z >> 16) | (va.w & 0xffff0000u);
                l.z = (vb.x >> 16) | (vb.y & 0xffff0000u);
                l.w = (vb.z >> 16) | (vb.w & 0xffff0000u);
                *(uint4*)&Ah[a] = h;
                *(uint4*)&Al[a] = l;
            }
        }
        if (cig < 3) { HM_ISSUE(cig + 1); }
        __syncthreads();
        __builtin_amdgcn_s_setprio(1);
        #pragma unroll 1
        for (int kk = 0; kk < 9; kk++) {
            int ky = kk / 3, kx = kk - 3*(kk/3);
            s16x8 ah[4], al[4];
            #pragma unroll
            for (int mf = 0; mf < 4; mf++) {
                int xq = (lane & 15) + 16*mf + kx;
                int a = (((lane >> 4)*4 + ky)*68 + xq)*8;
                ah[mf] = *(const s16x8*)&Ah[a];
                al[mf] = *(const s16x8*)&Al[a];
            }
            const unsigned short* wk = WFh + kk*65536 + cig*16384;
            #pragma unroll
            for (int nf = 0; nf < 2; nf++) {
                int nfg = w*2 + nf;
                s16x8 bh = *(const s16x8*)(wk + nfg*512 + lane*8);
                s16x8 bl = *(const s16x8*)(wk + 8192 + nfg*512 + lane*8);
                #pragma unroll
                for (int mf = 0; mf < 4; mf++) {
                    acc[mf][nf] = __builtin_amdgcn_mfma_f32_16x16x32_bf16(ah[mf], bh, acc[mf][nf], 0, 0, 0);
                    acc[mf][nf] = __builtin_amdgcn_mfma_f32_16x16x32_bf16(ah[mf], bl, acc[mf][nf], 0, 0, 0);
                    acc[mf][nf] = __builtin_amdgcn_mfma_f32_16x16x32_bf16(al[mf], bh, acc[mf][nf], 0, 0, 0);
                }
            }
        }
        __builtin_amdgcn_s_setprio(0);
    }
    #undef HM_ISSUE

    const float* b1p = head ? bb1 : db1;
    const float* w2p = head ? bw2 : dw2;
    const float* b2p = head ? bb2 : db2;
    const int NOUT = head ? 4 : 1;

    #pragma unroll
    for (int nf = 0; nf < 2; nf++) {
        float bv = b1p[(lane & 15) + (w*2 + nf)*16];
        #pragma unroll
        for (int mf = 0; mf < 4; mf++)
            #pragma unroll
            for (int r = 0; r < 4; r++)
                acc[mf][nf][r] = fmaxf(acc[mf][nf][r] + bv, 0.f);
    }

    for (int p = 0; p < NOUT; p++) {
        float wq0 = w2p[p*256 + (lane & 15) + (w*2 + 0)*16];
        float wq1 = w2p[p*256 + (lane & 15) + (w*2 + 1)*16];
        #pragma unroll
        for (int mf = 0; mf < 4; mf++) {
            #pragma unroll
            for (int r = 0; r < 4; r++) {
                float v = acc[mf][0][r]*wq0 + acc[mf][1][r]*wq1;
                v += __shfl_xor(v, 1);
                v += __shfl_xor(v, 2);
                v += __shfl_xor(v, 4);
                v += __shfl_xor(v, 8);
                if ((lane & 15) == 0)
                    red[w][p][mf*16 + (lane >> 4)*4 + r] = v;
            }
        }
    }
    __syncthreads();
    float* outp = head ? BF : SC;
    if (tid < NOUT*64) {
        int p = tid >> 6; int px = tid & 63;
        float v = b2p[p];
        #pragma unroll
        for (int ww = 0; ww < 8; ww++) v += red[ww][p][px];
        outp[((size_t)((b0 + imgl)*NOUT + p))*4096 + y*64 + px] = v;
    }
}

__global__ __launch_bounds__(256) void topk_k(
    const float* __restrict__ scores, const float* __restrict__ bflat,
    float* __restrict__ outp)
{
    __shared__ float sv[4096];
    __shared__ float rv[256];
    __shared__ int   ri[256];
    __shared__ float kv[8];
    __shared__ int   kidx[8];
    int b = blockIdx.x, t = threadIdx.x;
    for (int i = t; i < 4096; i += 256) sv[i] = scores[b*4096 + i];
    __syncthreads();
    for (int k = 0; k < 8; k++) {
        float bv = -INFINITY; int bi = 0x7fffffff;
        for (int i = t; i < 4096; i += 256) {
            float v = sv[i];
            if (v > bv || (v == bv && i < bi)) { bv = v; bi = i; }
        }
        rv[t] = bv; ri[t] = bi;
        __syncthreads();
        for (int s = 128; s > 0; s >>= 1) {
            if (t < s) {
                float v2 = rv[t+s]; int i2 = ri[t+s];
                if (v2 > rv[t] || (v2 == rv[t] && i2 < ri[t])) { rv[t] = v2; ri[t] = i2; }
            }
            __syncthreads();
        }
        if (t == 0) { kv[k] = rv[0]; kidx[k] = ri[0]; sv[ri[0]] = -INFINITY; }
        __syncthreads();
    }
    if (t < 32) {
        int k = t >> 2, c = t & 3;
        int idx = kidx[k];
        float s  = 1.f / (1.f + expf(-kv[k]));
        float lg = bflat[((size_t)(b*4 + c))*4096 + idx];
        float box = 512.f / (1.f + expf(-lg));
        outp[(b*8 + k)*4 + c] = (s > 0.5f) ? box : 0.f;
    }
}

extern "C" void kernel_launch(void* const* d_in, const int* in_sizes, int n_in,
                              void* d_out, int out_size, void* d_ws, size_t ws_size,
                              hipStream_t stream)
{
    const float* x   = (const float*)d_in[0];
    const float* w1  = (const float*)d_in[1];
    const float* b1  = (const float*)d_in[2];
    const float* g1  = (const float*)d_in[3];
    const float* be1 = (const float*)d_in[4];
    const float* m1  = (const float*)d_in[5];
    const float* v1  = (const float*)d_in[6];
    const float* w2  = (const float*)d_in[7];
    const float* b2  = (const float*)d_in[8];
    const float* g2  = (const float*)d_in[9];
    const float* be2 = (const float*)d_in[10];
    const float* m2  = (const float*)d_in[11];
    const float* v2  = (const float*)d_in[12];
    const float* w3  = (const float*)d_in[13];
    const float* b3  = (const float*)d_in[14];
    const float* g3  = (const float*)d_in[15];
    const float* be3 = (const float*)d_in[16];
    const float* m3  = (const float*)d_in[17];
    const float* v3  = (const float*)d_in[18];
    const float* dw1 = (const float*)d_in[19];
    const float* db1 = (const float*)d_in[20];
    const float* dw2 = (const float*)d_in[21];
    const float* db2 = (const float*)d_in[22];
    const float* bw1 = (const float*)d_in[23];
    const float* bb1 = (const float*)d_in[24];
    const float* bw2 = (const float*)d_in[25];
    const float* bb2 = (const float*)d_in[26];

    char*  wsb = (char*)d_ws;
    float*          W   = (float*)wsb;
    unsigned short* WF  = (unsigned short*)(wsb + 372992);
    unsigned short* W3F = (unsigned short*)(wsb + 2732288);
    float*          SC  = (float*)(wsb + 3027200);
    float*          BF  = (float*)(wsb + 3551488);
    unsigned short* A2H = (unsigned short*)(wsb + 5648640);
    unsigned short* A2L = (unsigned short*)(wsb + 22425856);
    unsigned*       A3P = (unsigned*)(wsb + 39203072);
    unsigned short* W2F = (unsigned short*)(wsb + 55980288);
    float* out = (float*)d_out;

    prep_k <<<365, 256, 0, stream>>>(w1,b1,g1,be1,m1,v1, w2,b2,g2,be2,m2,v2,
                                     w3,b3,g3,be3,m3,v3, W);
    prep2_k<<<4608, 256, 0, stream>>>(dw1, bw1, WF);
    prep3_k<<<576, 256, 0, stream>>>(w3, g3, v3, W3F);
    prep4_k<<<144, 256, 0, stream>>>(w2, g2, v2, W2F);

    for (int c = 0; c < 4; c++) {
        conv12mm_k<<<4096, 256, 0, stream>>>(x, W, W2F, A2H, A2L, c*8);
        conv3mm_k <<<1024, 256, 0, stream>>>(A2H, A2L, W3F, W + 93120, A3P);
        headmm_k  <<<dim3(512, 2), 512, 0, stream>>>(A3P, WF, db1, dw2, db2, bb1, bw2, bb2,
                                                     SC, BF, c*8);
    }
    topk_k<<<32, 256, 0, stream>>>(SC, BF, out);
}

// Round 17
// 650.350 us; speedup vs baseline: 1.2349x; 1.1511x over previous
//
#include <hip/hip_runtime.h>
#include <math.h>

#define EPSBN 1e-5f

typedef __attribute__((ext_vector_type(4))) float f32x4;
typedef __attribute__((ext_vector_type(8))) short s16x8;

__device__ __forceinline__ unsigned short f2bf(float f) {
    unsigned u = __builtin_bit_cast(unsigned, f);
    u = (u + 0x7fffu + ((u >> 16) & 1u)) >> 16;
    return (unsigned short)u;
}
__device__ __forceinline__ float bf2f(unsigned short s) {
    unsigned u = ((unsigned)s) << 16;
    return __builtin_bit_cast(float, u);
}

// ---------------- workspace layout (BYTE offsets), peak 56,054,016 B ----------------
// W @0 | WF @372,992 | W3F @2,732,288 | SC @3,027,200 | BF @3,551,488
// A2H @5,648,640 | A2L @22,425,856 | A3P @39,203,072 | W2F @55,980,288

__global__ __launch_bounds__(256) void prep_k(
    const float* __restrict__ w1, const float* __restrict__ b1, const float* __restrict__ g1,
    const float* __restrict__ be1, const float* __restrict__ m1, const float* __restrict__ v1,
    const float* __restrict__ w2, const float* __restrict__ b2, const float* __restrict__ g2,
    const float* __restrict__ be2, const float* __restrict__ m2, const float* __restrict__ v2,
    const float* __restrict__ w3, const float* __restrict__ b3, const float* __restrict__ g3,
    const float* __restrict__ be3, const float* __restrict__ m3, const float* __restrict__ v3,
    float* __restrict__ W)
{
    int i = blockIdx.x * 256 + threadIdx.x;
    if (i < 864) {
        int co = i & 31; int r = i >> 5; int ci = r % 3; int kk = r / 3;
        float A = g1[co] * rsqrtf(v1[co] + EPSBN);
        W[i] = w1[(co*3 + ci)*9 + kk] * A;
    } else if (i < 896) {
        int co = i - 864;
        float A = g1[co] * rsqrtf(v1[co] + EPSBN);
        W[i] = (b1[co] - m1[co]) * A + be1[co];
    } else if (i >= 19328 && i < 19392) {
        int co = i - 19328;
        float A = g2[co] * rsqrtf(v2[co] + EPSBN);
        W[i] = (b2[co] - m2[co]) * A + be2[co];
    } else if (i >= 93120 && i < 93248) {
        int co = i - 93120;
        float A = g3[co] * rsqrtf(v3[co] + EPSBN);
        W[i] = (b3[co] - m3[co]) * A + be3[co];
    }
}

__global__ __launch_bounds__(256) void prep2_k(
    const float* __restrict__ dw1, const float* __restrict__ bw1,
    unsigned short* __restrict__ WF)
{
    int i = blockIdx.x * 256 + threadIdx.x;
    if (i >= 1179648) return;
    int head = i / 589824;
    int r    = i - head * 589824;
    int kk   = r >> 16;
    int r2   = r & 65535;
    int cig  = r2 >> 14;
    int pl   = (r2 >> 13) & 1;
    int nf   = (r2 >> 9) & 15;
    int lane = (r2 >> 3) & 63;
    int j    = r2 & 7;
    int ci = cig*32 + (lane >> 4)*8 + j;
    int co = (lane & 15) + nf*16;
    const float* src = head ? bw1 : dw1;
    float w = src[(co*128 + ci)*9 + kk];
    unsigned short h = f2bf(w);
    WF[i] = pl ? f2bf(w - bf2f(h)) : h;
}

__global__ __launch_bounds__(256) void prep3_k(
    const float* __restrict__ w3, const float* __restrict__ g3, const float* __restrict__ v3,
    unsigned short* __restrict__ W3F)
{
    int i = blockIdx.x * 256 + threadIdx.x;
    if (i >= 147456) return;
    int kk = i >> 14;
    int r  = i & 16383;
    int cig = r >> 13;
    int pl  = (r >> 12) & 1;
    int nf  = (r >> 9) & 7;
    int lane = (r >> 3) & 63;
    int j   = r & 7;
    int ci = cig*32 + (lane >> 4)*8 + j;
    int co = nf*16 + (lane & 15);
    float A = g3[co] * rsqrtf(v3[co] + EPSBN);
    float w = w3[(co*64 + ci)*9 + kk] * A;
    unsigned short h = f2bf(w);
    W3F[i] = pl ? f2bf(w - bf2f(h)) : h;
}

__global__ __launch_bounds__(256) void prep4_k(
    const float* __restrict__ w2, const float* __restrict__ g2, const float* __restrict__ v2,
    unsigned short* __restrict__ W2F)
{
    int i = blockIdx.x * 256 + threadIdx.x;
    if (i >= 36864) return;
    int kk = i >> 12;
    int r  = i & 4095;
    int pl  = r >> 11;
    int nfg = (r >> 9) & 3;
    int lane = (r >> 3) & 63;
    int j   = r & 7;
    int ci = (lane >> 4)*8 + j;
    int co = nfg*16 + (lane & 15);
    float A = g2[co] * rsqrtf(v2[co] + EPSBN);
    float w = w2[(co*32 + ci)*9 + kk] * A;
    unsigned short h = f2bf(w);
    W2F[i] = pl ? f2bf(w - bf2f(h)) : h;
}

// ---------------- fused conv1(VALU)+conv2(MFMA): round-14 config (16x4, grid 2048) --
__global__ __launch_bounds__(256, 4) void conv12mm_k(
    const float* __restrict__ x, const float* __restrict__ W,
    const unsigned short* __restrict__ W2F,
    unsigned short* __restrict__ A2H, unsigned short* __restrict__ A2L, int b0)
{
    __shared__ __attribute__((aligned(16))) unsigned short Ah[9792];
    __shared__ __attribute__((aligned(16))) unsigned short Al[9792];

    const int tid  = threadIdx.x;
    const int lane = tid & 63;
    const int wv   = tid >> 6;
    const int m    = lane & 15;
    const int ks   = lane >> 4;

    const int bl   = blockIdx.x >> 8;
    const int tile = blockIdx.x & 255;
    const int OY = (tile >> 3) * 4;
    const int OX = (tile & 7) * 16;
    const int base1y = 2*OY - 1, base1x = 2*OX - 1;

    const float* xb = x + (size_t)(b0 + bl) * 3 * 262144;

    for (int t = tid; t < 297; t += 256) {
        int row = t / 33, lx = t - row*33;
        int y1 = base1y + row, x1 = base1x + lx;
        float c1[32];
        #pragma unroll
        for (int c = 0; c < 32; c++) c1[c] = 0.f;
        if (((unsigned)y1 < 256u) && ((unsigned)x1 < 256u)) {
            #pragma unroll
            for (int ky = 0; ky < 3; ky++) {
                int xy = 2*y1 + ky - 1;
                if ((unsigned)xy < 512u) {
                    #pragma unroll
                    for (int kx = 0; kx < 3; kx++) {
                        int xx = 2*x1 + kx - 1;
                        if ((unsigned)xx < 512u) {
                            int kk = ky*3 + kx;
                            #pragma unroll
                            for (int ci = 0; ci < 3; ci++) {
                                float v = xb[(size_t)ci*262144 + xy*512 + xx];
                                const float4* w4 = (const float4*)(W + (kk*3+ci)*32);
                                float4 wa = w4[0], wb = w4[1], wc = w4[2], wd = w4[3];
                                float4 we = w4[4], wf = w4[5], wg = w4[6], wh = w4[7];
                                c1[0]  = fmaf(v, wa.x, c1[0]);  c1[1]  = fmaf(v, wa.y, c1[1]);
                                c1[2]  = fmaf(v, wa.z, c1[2]);  c1[3]  = fmaf(v, wa.w, c1[3]);
                                c1[4]  = fmaf(v, wb.x, c1[4]);  c1[5]  = fmaf(v, wb.y, c1[5]);
                                c1[6]  = fmaf(v, wb.z, c1[6]);  c1[7]  = fmaf(v, wb.w, c1[7]);
                                c1[8]  = fmaf(v, wc.x, c1[8]);  c1[9]  = fmaf(v, wc.y, c1[9]);
                                c1[10] = fmaf(v, wc.z, c1[10]); c1[11] = fmaf(v, wc.w, c1[11]);
                                c1[12] = fmaf(v, wd.x, c1[12]); c1[13] = fmaf(v, wd.y, c1[13]);
                                c1[14] = fmaf(v, wd.z, c1[14]); c1[15] = fmaf(v, wd.w, c1[15]);
                                c1[16] = fmaf(v, we.x, c1[16]); c1[17] = fmaf(v, we.y, c1[17]);
                                c1[18] = fmaf(v, we.z, c1[18]); c1[19] = fmaf(v, we.w, c1[19]);
                                c1[20] = fmaf(v, wf.x, c1[20]); c1[21] = fmaf(v, wf.y, c1[21]);
                                c1[22] = fmaf(v, wf.z, c1[22]); c1[23] = fmaf(v, wf.w, c1[23]);
                                c1[24] = fmaf(v, wg.x, c1[24]); c1[25] = fmaf(v, wg.y, c1[25]);
                                c1[26] = fmaf(v, wg.z, c1[26]); c1[27] = fmaf(v, wg.w, c1[27]);
                                c1[28] = fmaf(v, wh.x, c1[28]); c1[29] = fmaf(v, wh.y, c1[29]);
                                c1[30] = fmaf(v, wh.z, c1[30]); c1[31] = fmaf(v, wh.w, c1[31]);
                            }
                        }
                    }
                }
            }
            #pragma unroll
            for (int c = 0; c < 32; c++)
                c1[c] = fmaxf(c1[c] + W[864 + c], 0.f);
        }
        int xi = (lx & 1)*17 + (lx >> 1);
        #pragma unroll
        for (int kg = 0; kg < 4; kg++) {
            uint4 h, l;
            unsigned hw[4], lw[4];
            #pragma unroll
            for (int q = 0; q < 4; q++) {
                float r0 = c1[kg*8 + 2*q], r1 = c1[kg*8 + 2*q + 1];
                unsigned short h0 = f2bf(r0), h1 = f2bf(r1);
                unsigned short l0 = f2bf(r0 - bf2f(h0)), l1 = f2bf(r1 - bf2f(h1));
                hw[q] = (unsigned)h0 | ((unsigned)h1 << 16);
                lw[q] = (unsigned)l0 | ((unsigned)l1 << 16);
            }
            h.x = hw[0]; h.y = hw[1]; h.z = hw[2]; h.w = hw[3];
            l.x = lw[0]; l.y = lw[1]; l.z = lw[2]; l.w = lw[3];
            int a = ((kg*9 + row)*34 + xi)*8;
            *(uint4*)&Ah[a] = h;
            *(uint4*)&Al[a] = l;
        }
    }
    __syncthreads();

    f32x4 acc[4];
    #pragma unroll
    for (int mf = 0; mf < 4; mf++) { f32x4 z = {0.f,0.f,0.f,0.f}; acc[mf] = z; }

    for (int ky = 0; ky < 3; ky++) {
        for (int kx = 0; kx < 3; kx++) {
            int kk = ky*3 + kx;
            int xib = (kx & 1)*17 + (kx >> 1);
            s16x8 ah[4], al[4];
            #pragma unroll
            for (int mf = 0; mf < 4; mf++) {
                int hy = 2*mf + ky;
                int a = ((ks*9 + hy)*34 + xib + m)*8;
                ah[mf] = *(const s16x8*)&Ah[a];
                al[mf] = *(const s16x8*)&Al[a];
            }
            const unsigned short* wb = W2F + kk*4096;
            s16x8 bh  = *(const s16x8*)(wb + wv*512 + lane*8);
            s16x8 blo = *(const s16x8*)(wb + 2048 + wv*512 + lane*8);
            #pragma unroll
            for (int mf = 0; mf < 4; mf++) {
                acc[mf] = __builtin_amdgcn_mfma_f32_16x16x32_bf16(ah[mf], bh,  acc[mf], 0, 0, 0);
                acc[mf] = __builtin_amdgcn_mfma_f32_16x16x32_bf16(ah[mf], blo, acc[mf], 0, 0, 0);
                acc[mf] = __builtin_amdgcn_mfma_f32_16x16x32_bf16(al[mf], bh,  acc[mf], 0, 0, 0);
            }
        }
    }

    const int co = wv*16 + m;
    const float bv = W[19328 + co];
    #pragma unroll
    for (int mf = 0; mf < 4; mf++) {
        int y = OY + mf;
        #pragma unroll
        for (int r = 0; r < 4; r++) {
            int xo = OX + ks*4 + r;
            float rv = fmaxf(acc[mf][r] + bv, 0.f);
            unsigned short h = f2bf(rv);
            unsigned short l = f2bf(rv - bf2f(h));
            size_t a = ((size_t)(bl*16384 + y*128 + xo))*64 + co;
            A2H[a] = h;
            A2L[a] = l;
        }
    }
}

// ---------------- conv3 MFMA: round-14 config (full row, grid 512) ------------------
__global__ __launch_bounds__(256, 2) void conv3mm_k(
    const unsigned short* __restrict__ A2H, const unsigned short* __restrict__ A2L,
    const unsigned short* __restrict__ W3F, const float* __restrict__ bias,
    unsigned* __restrict__ A3P)
{
    const int tid  = threadIdx.x;
    const int lane = tid & 63;
    const int w    = tid >> 6;
    const int bl   = blockIdx.x >> 6;
    const int y    = blockIdx.x & 63;
    const int m    = lane & 15;
    const int ks   = lane >> 4;

    f32x4 acc[4][2];
    #pragma unroll
    for (int mf = 0; mf < 4; mf++)
        #pragma unroll
        for (int nfl = 0; nfl < 2; nfl++) {
            f32x4 z = {0.f, 0.f, 0.f, 0.f};
            acc[mf][nfl] = z;
        }

    const size_t ibase = (size_t)bl * 16384 * 64;

    for (int ky = 0; ky < 3; ky++) {
        int iy = 2*y + ky - 1;
        if ((unsigned)iy >= 128u) continue;
        for (int kx = 0; kx < 3; kx++) {
            int kk = ky*3 + kx;
            #pragma unroll
            for (int cig = 0; cig < 2; cig++) {
                s16x8 ah[4], al[4];
                #pragma unroll
                for (int mf = 0; mf < 4; mf++) {
                    int xo = mf*16 + m;
                    int ix = 2*xo + kx - 1;
                    bool v = ix >= 0;
                    int ixc = v ? ix : 0;
                    size_t a = ibase + ((size_t)iy*128 + ixc)*64 + cig*32 + ks*8;
                    s16x8 zh = {0,0,0,0,0,0,0,0};
                    s16x8 th = *(const s16x8*)(A2H + a);
                    s16x8 tl = *(const s16x8*)(A2L + a);
                    ah[mf] = v ? th : zh;
                    al[mf] = v ? tl : zh;
                }
                const unsigned short* wb = W3F + (kk*2 + cig)*8192;
                #pragma unroll
                for (int nfl = 0; nfl < 2; nfl++) {
                    int nfg = w*2 + nfl;
                    s16x8 bh  = *(const s16x8*)(wb + nfg*512 + lane*8);
                    s16x8 blo = *(const s16x8*)(wb + 4096 + nfg*512 + lane*8);
                    #pragma unroll
                    for (int mf = 0; mf < 4; mf++) {
                        acc[mf][nfl] = __builtin_amdgcn_mfma_f32_16x16x32_bf16(ah[mf], bh,  acc[mf][nfl], 0, 0, 0);
                        acc[mf][nfl] = __builtin_amdgcn_mfma_f32_16x16x32_bf16(ah[mf], blo, acc[mf][nfl], 0, 0, 0);
                        acc[mf][nfl] = __builtin_amdgcn_mfma_f32_16x16x32_bf16(al[mf], bh,  acc[mf][nfl], 0, 0, 0);
                    }
                }
            }
        }
    }

    const size_t obase = ((size_t)(bl*64 + y))*64*128;
    #pragma unroll
    for (int nfl = 0; nfl < 2; nfl++) {
        int co = (w*2 + nfl)*16 + m;
        float bv = bias[co];
        #pragma unroll
        for (int mf = 0; mf < 4; mf++) {
            #pragma unroll
            for (int r = 0; r < 4; r++) {
                float rv = fmaxf(acc[mf][nfl][r] + bv, 0.f);
                unsigned short h = f2bf(rv);
                unsigned short l = f2bf(rv - bf2f(h));
                int xo = mf*16 + ks*4 + r;
                A3P[obase + (size_t)xo*128 + co] = (unsigned)h | ((unsigned)l << 16);
            }
        }
    }
}

// ---------------- MFMA head: det = split-bf16 (3 MFMA), bbox = plain bf16 (1 MFMA) --
// Only det scores feed top-k/mask (rank-sensitive); bbox logits tolerate ~0.4% rel
// error (box error ~0.2 << threshold 5.48). head is block-uniform -> clean branch.
__global__ __launch_bounds__(512, 2) void headmm_k(
    const unsigned* __restrict__ A3P, const unsigned short* __restrict__ WF,
    const float* __restrict__ db1, const float* __restrict__ dw2, const float* __restrict__ db2,
    const float* __restrict__ bb1, const float* __restrict__ bw2, const float* __restrict__ bb2,
    float* __restrict__ SC, float* __restrict__ BF, int b0)
{
    __shared__ __attribute__((aligned(16))) unsigned short Ah[8704];
    __shared__ __attribute__((aligned(16))) unsigned short Al[8704];
    __shared__ float red[8][4][64];

    const int tid  = threadIdx.x;
    const int lane = tid & 63;
    const int w    = tid >> 6;
    const int head = blockIdx.y;
    const int imgl = blockIdx.x >> 6;
    const int y    = blockIdx.x & 63;

    f32x4 acc[4][2];
    #pragma unroll
    for (int mf = 0; mf < 4; mf++)
        #pragma unroll
        for (int nf = 0; nf < 2; nf++) {
            f32x4 z = {0.f, 0.f, 0.f, 0.f};
            acc[mf][nf] = z;
        }

    const unsigned* abase = A3P + (size_t)imgl * 64 * 64 * 128;
    const unsigned short* WFh = WF + head * 589824;

    uint4 pva[2], pvb[2];
    #define HM_ISSUE(CIG)                                                          \
        _Pragma("unroll")                                                          \
        for (int it = 0; it < 2; it++) {                                           \
            int t = tid + it*512;                                                  \
            uint4 z4 = {0u,0u,0u,0u};                                              \
            pva[it] = z4; pvb[it] = z4;                                            \
            if (t < 792) {                                                         \
                int kgrp = t & 3; int q = t >> 2;                                  \
                int xi = q % 66;  int row = q / 66;                                \
                int gr = y + row - 1, gx = xi - 1;                                 \
                if (((unsigned)gr < 64u) && ((unsigned)gx < 64u)) {                \
                    const uint4* p = (const uint4*)(abase + ((size_t)gr*64 + gx)*128 \
                                                    + (CIG)*32 + kgrp*8);          \
                    pva[it] = p[0]; pvb[it] = p[1];                                \
                }                                                                  \
            }                                                                      \
        }

    HM_ISSUE(0);
    for (int cig = 0; cig < 4; cig++) {
        __syncthreads();
        #pragma unroll
        for (int it = 0; it < 2; it++) {
            int t = tid + it*512;
            if (t < 792) {
                int kgrp = t & 3; int q = t >> 2;
                int xi = q % 66;  int row = q / 66;
                int a = ((kgrp*4 + row)*68 + xi)*8;
                uint4 va = pva[it], vb = pvb[it];
                uint4 h, l;
                h.x = (va.x & 0xffffu) | (va.y << 16);
                h.y = (va.z & 0xffffu) | (va.w << 16);
                h.z = (vb.x & 0xffffu) | (vb.y << 16);
                h.w = (vb.z & 0xffffu) | (vb.w << 16);
                l.x = (va.x >> 16) | (va.y & 0xffff0000u);
                l.y = (va.z >> 16) | (va.w & 0xffff0000u);
                l.z = (vb.x >> 16) | (vb.y & 0xffff0000u);
                l.w = (vb.z >> 16) | (vb.w & 0xffff0000u);
                *(uint4*)&Ah[a] = h;
                *(uint4*)&Al[a] = l;
            }
        }
        if (cig < 3) { HM_ISSUE(cig + 1); }
        __syncthreads();
        __builtin_amdgcn_s_setprio(1);
        if (head == 0) {
            // det head: full split-bf16 (rank-critical)
            #pragma unroll 1
            for (int kk = 0; kk < 9; kk++) {
                int ky = kk / 3, kx = kk - 3*(kk/3);
                s16x8 ah[4], al[4];
                #pragma unroll
                for (int mf = 0; mf < 4; mf++) {
                    int xq = (lane & 15) + 16*mf + kx;
                    int a = (((lane >> 4)*4 + ky)*68 + xq)*8;
                    ah[mf] = *(const s16x8*)&Ah[a];
                    al[mf] = *(const s16x8*)&Al[a];
                }
                const unsigned short* wk = WFh + kk*65536 + cig*16384;
                #pragma unroll
                for (int nf = 0; nf < 2; nf++) {
                    int nfg = w*2 + nf;
                    s16x8 bh = *(const s16x8*)(wk + nfg*512 + lane*8);
                    s16x8 bl = *(const s16x8*)(wk + 8192 + nfg*512 + lane*8);
                    #pragma unroll
                    for (int mf = 0; mf < 4; mf++) {
                        acc[mf][nf] = __builtin_amdgcn_mfma_f32_16x16x32_bf16(ah[mf], bh, acc[mf][nf], 0, 0, 0);
                        acc[mf][nf] = __builtin_amdgcn_mfma_f32_16x16x32_bf16(ah[mf], bl, acc[mf][nf], 0, 0, 0);
                        acc[mf][nf] = __builtin_amdgcn_mfma_f32_16x16x32_bf16(al[mf], bh, acc[mf][nf], 0, 0, 0);
                    }
                }
            }
        } else {
            // bbox head: plain bf16 (1 MFMA) — error ~0.2 on boxes, threshold 5.48
            #pragma unroll 1
            for (int kk = 0; kk < 9; kk++) {
                int ky = kk / 3, kx = kk - 3*(kk/3);
                s16x8 ah[4];
                #pragma unroll
                for (int mf = 0; mf < 4; mf++) {
                    int xq = (lane & 15) + 16*mf + kx;
                    int a = (((lane >> 4)*4 + ky)*68 + xq)*8;
                    ah[mf] = *(const s16x8*)&Ah[a];
                }
                const unsigned short* wk = WFh + kk*65536 + cig*16384;
                #pragma unroll
                for (int nf = 0; nf < 2; nf++) {
                    int nfg = w*2 + nf;
                    s16x8 bh = *(const s16x8*)(wk + nfg*512 + lane*8);
                    #pragma unroll
                    for (int mf = 0; mf < 4; mf++)
                        acc[mf][nf] = __builtin_amdgcn_mfma_f32_16x16x32_bf16(ah[mf], bh, acc[mf][nf], 0, 0, 0);
                }
            }
        }
        __builtin_amdgcn_s_setprio(0);
    }
    #undef HM_ISSUE

    const float* b1p = head ? bb1 : db1;
    const float* w2p = head ? bw2 : dw2;
    const float* b2p = head ? bb2 : db2;
    const int NOUT = head ? 4 : 1;

    #pragma unroll
    for (int nf = 0; nf < 2; nf++) {
        float bv = b1p[(lane & 15) + (w*2 + nf)*16];
        #pragma unroll
        for (int mf = 0; mf < 4; mf++)
            #pragma unroll
            for (int r = 0; r < 4; r++)
                acc[mf][nf][r] = fmaxf(acc[mf][nf][r] + bv, 0.f);
    }

    for (int p = 0; p < NOUT; p++) {
        float wq0 = w2p[p*256 + (lane & 15) + (w*2 + 0)*16];
        float wq1 = w2p[p*256 + (lane & 15) + (w*2 + 1)*16];
        #pragma unroll
        for (int mf = 0; mf < 4; mf++) {
            #pragma unroll
            for (int r = 0; r < 4; r++) {
                float v = acc[mf][0][r]*wq0 + acc[mf][1][r]*wq1;
                v += __shfl_xor(v, 1);
                v += __shfl_xor(v, 2);
                v += __shfl_xor(v, 4);
                v += __shfl_xor(v, 8);
                if ((lane & 15) == 0)
                    red[w][p][mf*16 + (lane >> 4)*4 + r] = v;
            }
        }
    }
    __syncthreads();
    float* outp = head ? BF : SC;
    if (tid < NOUT*64) {
        int p = tid >> 6; int px = tid & 63;
        float v = b2p[p];
        #pragma unroll
        for (int ww = 0; ww < 8; ww++) v += red[ww][p][px];
        outp[((size_t)((b0 + imgl)*NOUT + p))*4096 + y*64 + px] = v;
    }
}

__global__ __launch_bounds__(256) void topk_k(
    const float* __restrict__ scores, const float* __restrict__ bflat,
    float* __restrict__ outp)
{
    __shared__ float sv[4096];
    __shared__ float rv[256];
    __shared__ int   ri[256];
    __shared__ float kv[8];
    __shared__ int   kidx[8];
    int b = blockIdx.x, t = threadIdx.x;
    for (int i = t; i < 4096; i += 256) sv[i] = scores[b*4096 + i];
    __syncthreads();
    for (int k = 0; k < 8; k++) {
        float bv = -INFINITY; int bi = 0x7fffffff;
        for (int i = t; i < 4096; i += 256) {
            float v = sv[i];
            if (v > bv || (v == bv && i < bi)) { bv = v; bi = i; }
        }
        rv[t] = bv; ri[t] = bi;
        __syncthreads();
        for (int s = 128; s > 0; s >>= 1) {
            if (t < s) {
                float v2 = rv[t+s]; int i2 = ri[t+s];
                if (v2 > rv[t] || (v2 == rv[t] && i2 < ri[t])) { rv[t] = v2; ri[t] = i2; }
            }
            __syncthreads();
        }
        if (t == 0) { kv[k] = rv[0]; kidx[k] = ri[0]; sv[ri[0]] = -INFINITY; }
        __syncthreads();
    }
    if (t < 32) {
        int k = t >> 2, c = t & 3;
        int idx = kidx[k];
        float s  = 1.f / (1.f + expf(-kv[k]));
        float lg = bflat[((size_t)(b*4 + c))*4096 + idx];
        float box = 512.f / (1.f + expf(-lg));
        outp[(b*8 + k)*4 + c] = (s > 0.5f) ? box : 0.f;
    }
}

extern "C" void kernel_launch(void* const* d_in, const int* in_sizes, int n_in,
                              void* d_out, int out_size, void* d_ws, size_t ws_size,
                              hipStream_t stream)
{
    const float* x   = (const float*)d_in[0];
    const float* w1  = (const float*)d_in[1];
    const float* b1  = (const float*)d_in[2];
    const float* g1  = (const float*)d_in[3];
    const float* be1 = (const float*)d_in[4];
    const float* m1  = (const float*)d_in[5];
    const float* v1  = (const float*)d_in[6];
    const float* w2  = (const float*)d_in[7];
    const float* b2  = (const float*)d_in[8];
    const float* g2  = (const float*)d_in[9];
    const float* be2 = (const float*)d_in[10];
    const float* m2  = (const float*)d_in[11];
    const float* v2  = (const float*)d_in[12];
    const float* w3  = (const float*)d_in[13];
    const float* b3  = (const float*)d_in[14];
    const float* g3  = (const float*)d_in[15];
    const float* be3 = (const float*)d_in[16];
    const float* m3  = (const float*)d_in[17];
    const float* v3  = (const float*)d_in[18];
    const float* dw1 = (const float*)d_in[19];
    const float* db1 = (const float*)d_in[20];
    const float* dw2 = (const float*)d_in[21];
    const float* db2 = (const float*)d_in[22];
    const float* bw1 = (const float*)d_in[23];
    const float* bb1 = (const float*)d_in[24];
    const float* bw2 = (const float*)d_in[25];
    const float* bb2 = (const float*)d_in[26];

    char*  wsb = (char*)d_ws;
    float*          W   = (float*)wsb;
    unsigned short* WF  = (unsigned short*)(wsb + 372992);
    unsigned short* W3F = (unsigned short*)(wsb + 2732288);
    float*          SC  = (float*)(wsb + 3027200);
    float*          BF  = (float*)(wsb + 3551488);
    unsigned short* A2H = (unsigned short*)(wsb + 5648640);
    unsigned short* A2L = (unsigned short*)(wsb + 22425856);
    unsigned*       A3P = (unsigned*)(wsb + 39203072);
    unsigned short* W2F = (unsigned short*)(wsb + 55980288);
    float* out = (float*)d_out;

    prep_k <<<365, 256, 0, stream>>>(w1,b1,g1,be1,m1,v1, w2,b2,g2,be2,m2,v2,
                                     w3,b3,g3,be3,m3,v3, W);
    prep2_k<<<4608, 256, 0, stream>>>(dw1, bw1, WF);
    prep3_k<<<576, 256, 0, stream>>>(w3, g3, v3, W3F);
    prep4_k<<<144, 256, 0, stream>>>(w2, g2, v2, W2F);

    for (int c = 0; c < 4; c++) {
        conv12mm_k<<<2048, 256, 0, stream>>>(x, W, W2F, A2H, A2L, c*8);
        conv3mm_k <<<512, 256, 0, stream>>>(A2H, A2L, W3F, W + 93120, A3P);
        headmm_k  <<<dim3(512, 2), 512, 0, stream>>>(A3P, WF, db1, dw2, db2, bb1, bw2, bb2,
                                                     SC, BF, c*8);
    }
    topk_k<<<32, 256, 0, stream>>>(SC, BF, out);
}

// Round 18
// 649.810 us; speedup vs baseline: 1.2359x; 1.0008x over previous
//
#include <hip/hip_runtime.h>
#include <math.h>

#define EPSBN 1e-5f

typedef __attribute__((ext_vector_type(4))) float f32x4;
typedef __attribute__((ext_vector_type(8))) short s16x8;

__device__ __forceinline__ unsigned short f2bf(float f) {
    unsigned u = __builtin_bit_cast(unsigned, f);
    u = (u + 0x7fffu + ((u >> 16) & 1u)) >> 16;
    return (unsigned short)u;
}
__device__ __forceinline__ float bf2f(unsigned short s) {
    unsigned u = ((unsigned)s) << 16;
    return __builtin_bit_cast(float, u);
}

// ---------------- workspace layout (BYTE offsets), peak 56,054,016 B ----------------
// W @0 | WF @372,992 | W3F @2,732,288 | SC @3,027,200 | BF @3,551,488
// A2H @5,648,640 | A2L @22,425,856 | A3P @39,203,072 | W2F @55,980,288

__global__ __launch_bounds__(256) void prep_k(
    const float* __restrict__ w1, const float* __restrict__ b1, const float* __restrict__ g1,
    const float* __restrict__ be1, const float* __restrict__ m1, const float* __restrict__ v1,
    const float* __restrict__ w2, const float* __restrict__ b2, const float* __restrict__ g2,
    const float* __restrict__ be2, const float* __restrict__ m2, const float* __restrict__ v2,
    const float* __restrict__ w3, const float* __restrict__ b3, const float* __restrict__ g3,
    const float* __restrict__ be3, const float* __restrict__ m3, const float* __restrict__ v3,
    float* __restrict__ W)
{
    int i = blockIdx.x * 256 + threadIdx.x;
    if (i < 864) {
        int co = i & 31; int r = i >> 5; int ci = r % 3; int kk = r / 3;
        float A = g1[co] * rsqrtf(v1[co] + EPSBN);
        W[i] = w1[(co*3 + ci)*9 + kk] * A;
    } else if (i < 896) {
        int co = i - 864;
        float A = g1[co] * rsqrtf(v1[co] + EPSBN);
        W[i] = (b1[co] - m1[co]) * A + be1[co];
    } else if (i >= 19328 && i < 19392) {
        int co = i - 19328;
        float A = g2[co] * rsqrtf(v2[co] + EPSBN);
        W[i] = (b2[co] - m2[co]) * A + be2[co];
    } else if (i >= 93120 && i < 93248) {
        int co = i - 93120;
        float A = g3[co] * rsqrtf(v3[co] + EPSBN);
        W[i] = (b3[co] - m3[co]) * A + be3[co];
    }
}

__global__ __launch_bounds__(256) void prep2_k(
    const float* __restrict__ dw1, const float* __restrict__ bw1,
    unsigned short* __restrict__ WF)
{
    int i = blockIdx.x * 256 + threadIdx.x;
    if (i >= 1179648) return;
    int head = i / 589824;
    int r    = i - head * 589824;
    int kk   = r >> 16;
    int r2   = r & 65535;
    int cig  = r2 >> 14;
    int pl   = (r2 >> 13) & 1;
    int nf   = (r2 >> 9) & 15;
    int lane = (r2 >> 3) & 63;
    int j    = r2 & 7;
    int ci = cig*32 + (lane >> 4)*8 + j;
    int co = (lane & 15) + nf*16;
    const float* src = head ? bw1 : dw1;
    float w = src[(co*128 + ci)*9 + kk];
    unsigned short h = f2bf(w);
    WF[i] = pl ? f2bf(w - bf2f(h)) : h;
}

__global__ __launch_bounds__(256) void prep3_k(
    const float* __restrict__ w3, const float* __restrict__ g3, const float* __restrict__ v3,
    unsigned short* __restrict__ W3F)
{
    int i = blockIdx.x * 256 + threadIdx.x;
    if (i >= 147456) return;
    int kk = i >> 14;
    int r  = i & 16383;
    int cig = r >> 13;
    int pl  = (r >> 12) & 1;
    int nf  = (r >> 9) & 7;
    int lane = (r >> 3) & 63;
    int j   = r & 7;
    int ci = cig*32 + (lane >> 4)*8 + j;
    int co = nf*16 + (lane & 15);
    float A = g3[co] * rsqrtf(v3[co] + EPSBN);
    float w = w3[(co*64 + ci)*9 + kk] * A;
    unsigned short h = f2bf(w);
    W3F[i] = pl ? f2bf(w - bf2f(h)) : h;
}

__global__ __launch_bounds__(256) void prep4_k(
    const float* __restrict__ w2, const float* __restrict__ g2, const float* __restrict__ v2,
    unsigned short* __restrict__ W2F)
{
    int i = blockIdx.x * 256 + threadIdx.x;
    if (i >= 36864) return;
    int kk = i >> 12;
    int r  = i & 4095;
    int pl  = r >> 11;
    int nfg = (r >> 9) & 3;
    int lane = (r >> 3) & 63;
    int j   = r & 7;
    int ci = (lane >> 4)*8 + j;
    int co = nfg*16 + (lane & 15);
    float A = g2[co] * rsqrtf(v2[co] + EPSBN);
    float w = w2[(co*32 + ci)*9 + kk] * A;
    unsigned short h = f2bf(w);
    W2F[i] = pl ? f2bf(w - bf2f(h)) : h;
}

// ---------------- fused conv1(VALU)+conv2(MFMA): round-14 config (16x4, grid 2048) --
__global__ __launch_bounds__(256, 4) void conv12mm_k(
    const float* __restrict__ x, const float* __restrict__ W,
    const unsigned short* __restrict__ W2F,
    unsigned short* __restrict__ A2H, unsigned short* __restrict__ A2L, int b0)
{
    __shared__ __attribute__((aligned(16))) unsigned short Ah[9792];
    __shared__ __attribute__((aligned(16))) unsigned short Al[9792];

    const int tid  = threadIdx.x;
    const int lane = tid & 63;
    const int wv   = tid >> 6;
    const int m    = lane & 15;
    const int ks   = lane >> 4;

    const int bl   = blockIdx.x >> 8;
    const int tile = blockIdx.x & 255;
    const int OY = (tile >> 3) * 4;
    const int OX = (tile & 7) * 16;
    const int base1y = 2*OY - 1, base1x = 2*OX - 1;

    const float* xb = x + (size_t)(b0 + bl) * 3 * 262144;

    for (int t = tid; t < 297; t += 256) {
        int row = t / 33, lx = t - row*33;
        int y1 = base1y + row, x1 = base1x + lx;
        float c1[32];
        #pragma unroll
        for (int c = 0; c < 32; c++) c1[c] = 0.f;
        if (((unsigned)y1 < 256u) && ((unsigned)x1 < 256u)) {
            #pragma unroll
            for (int ky = 0; ky < 3; ky++) {
                int xy = 2*y1 + ky - 1;
                if ((unsigned)xy < 512u) {
                    #pragma unroll
                    for (int kx = 0; kx < 3; kx++) {
                        int xx = 2*x1 + kx - 1;
                        if ((unsigned)xx < 512u) {
                            int kk = ky*3 + kx;
                            #pragma unroll
                            for (int ci = 0; ci < 3; ci++) {
                                float v = xb[(size_t)ci*262144 + xy*512 + xx];
                                const float4* w4 = (const float4*)(W + (kk*3+ci)*32);
                                float4 wa = w4[0], wb = w4[1], wc = w4[2], wd = w4[3];
                                float4 we = w4[4], wf = w4[5], wg = w4[6], wh = w4[7];
                                c1[0]  = fmaf(v, wa.x, c1[0]);  c1[1]  = fmaf(v, wa.y, c1[1]);
                                c1[2]  = fmaf(v, wa.z, c1[2]);  c1[3]  = fmaf(v, wa.w, c1[3]);
                                c1[4]  = fmaf(v, wb.x, c1[4]);  c1[5]  = fmaf(v, wb.y, c1[5]);
                                c1[6]  = fmaf(v, wb.z, c1[6]);  c1[7]  = fmaf(v, wb.w, c1[7]);
                                c1[8]  = fmaf(v, wc.x, c1[8]);  c1[9]  = fmaf(v, wc.y, c1[9]);
                                c1[10] = fmaf(v, wc.z, c1[10]); c1[11] = fmaf(v, wc.w, c1[11]);
                                c1[12] = fmaf(v, wd.x, c1[12]); c1[13] = fmaf(v, wd.y, c1[13]);
                                c1[14] = fmaf(v, wd.z, c1[14]); c1[15] = fmaf(v, wd.w, c1[15]);
                                c1[16] = fmaf(v, we.x, c1[16]); c1[17] = fmaf(v, we.y, c1[17]);
                                c1[18] = fmaf(v, we.z, c1[18]); c1[19] = fmaf(v, we.w, c1[19]);
                                c1[20] = fmaf(v, wf.x, c1[20]); c1[21] = fmaf(v, wf.y, c1[21]);
                                c1[22] = fmaf(v, wf.z, c1[22]); c1[23] = fmaf(v, wf.w, c1[23]);
                                c1[24] = fmaf(v, wg.x, c1[24]); c1[25] = fmaf(v, wg.y, c1[25]);
                                c1[26] = fmaf(v, wg.z, c1[26]); c1[27] = fmaf(v, wg.w, c1[27]);
                                c1[28] = fmaf(v, wh.x, c1[28]); c1[29] = fmaf(v, wh.y, c1[29]);
                                c1[30] = fmaf(v, wh.z, c1[30]); c1[31] = fmaf(v, wh.w, c1[31]);
                            }
                        }
                    }
                }
            }
            #pragma unroll
            for (int c = 0; c < 32; c++)
                c1[c] = fmaxf(c1[c] + W[864 + c], 0.f);
        }
        int xi = (lx & 1)*17 + (lx >> 1);
        #pragma unroll
        for (int kg = 0; kg < 4; kg++) {
            uint4 h, l;
            unsigned hw[4], lw[4];
            #pragma unroll
            for (int q = 0; q < 4; q++) {
                float r0 = c1[kg*8 + 2*q], r1 = c1[kg*8 + 2*q + 1];
                unsigned short h0 = f2bf(r0), h1 = f2bf(r1);
                unsigned short l0 = f2bf(r0 - bf2f(h0)), l1 = f2bf(r1 - bf2f(h1));
                hw[q] = (unsigned)h0 | ((unsigned)h1 << 16);
                lw[q] = (unsigned)l0 | ((unsigned)l1 << 16);
            }
            h.x = hw[0]; h.y = hw[1]; h.z = hw[2]; h.w = hw[3];
            l.x = lw[0]; l.y = lw[1]; l.z = lw[2]; l.w = lw[3];
            int a = ((kg*9 + row)*34 + xi)*8;
            *(uint4*)&Ah[a] = h;
            *(uint4*)&Al[a] = l;
        }
    }
    __syncthreads();

    f32x4 acc[4];
    #pragma unroll
    for (int mf = 0; mf < 4; mf++) { f32x4 z = {0.f,0.f,0.f,0.f}; acc[mf] = z; }

    for (int ky = 0; ky < 3; ky++) {
        for (int kx = 0; kx < 3; kx++) {
            int kk = ky*3 + kx;
            int xib = (kx & 1)*17 + (kx >> 1);
            s16x8 ah[4], al[4];
            #pragma unroll
            for (int mf = 0; mf < 4; mf++) {
                int hy = 2*mf + ky;
                int a = ((ks*9 + hy)*34 + xib + m)*8;
                ah[mf] = *(const s16x8*)&Ah[a];
                al[mf] = *(const s16x8*)&Al[a];
            }
            const unsigned short* wb = W2F + kk*4096;
            s16x8 bh  = *(const s16x8*)(wb + wv*512 + lane*8);
            s16x8 blo = *(const s16x8*)(wb + 2048 + wv*512 + lane*8);
            #pragma unroll
            for (int mf = 0; mf < 4; mf++) {
                acc[mf] = __builtin_amdgcn_mfma_f32_16x16x32_bf16(ah[mf], bh,  acc[mf], 0, 0, 0);
                acc[mf] = __builtin_amdgcn_mfma_f32_16x16x32_bf16(ah[mf], blo, acc[mf], 0, 0, 0);
                acc[mf] = __builtin_amdgcn_mfma_f32_16x16x32_bf16(al[mf], bh,  acc[mf], 0, 0, 0);
            }
        }
    }

    const int co = wv*16 + m;
    const float bv = W[19328 + co];
    #pragma unroll
    for (int mf = 0; mf < 4; mf++) {
        int y = OY + mf;
        #pragma unroll
        for (int r = 0; r < 4; r++) {
            int xo = OX + ks*4 + r;
            float rv = fmaxf(acc[mf][r] + bv, 0.f);
            unsigned short h = f2bf(rv);
            unsigned short l = f2bf(rv - bf2f(h));
            size_t a = ((size_t)(bl*16384 + y*128 + xo))*64 + co;
            A2H[a] = h;
            A2L[a] = l;
        }
    }
}

// ---------------- conv3 MFMA: round-14 config (full row, grid 512) ------------------
__global__ __launch_bounds__(256, 2) void conv3mm_k(
    const unsigned short* __restrict__ A2H, const unsigned short* __restrict__ A2L,
    const unsigned short* __restrict__ W3F, const float* __restrict__ bias,
    unsigned* __restrict__ A3P)
{
    const int tid  = threadIdx.x;
    const int lane = tid & 63;
    const int w    = tid >> 6;
    const int bl   = blockIdx.x >> 6;
    const int y    = blockIdx.x & 63;
    const int m    = lane & 15;
    const int ks   = lane >> 4;

    f32x4 acc[4][2];
    #pragma unroll
    for (int mf = 0; mf < 4; mf++)
        #pragma unroll
        for (int nfl = 0; nfl < 2; nfl++) {
            f32x4 z = {0.f, 0.f, 0.f, 0.f};
            acc[mf][nfl] = z;
        }

    const size_t ibase = (size_t)bl * 16384 * 64;

    for (int ky = 0; ky < 3; ky++) {
        int iy = 2*y + ky - 1;
        if ((unsigned)iy >= 128u) continue;
        for (int kx = 0; kx < 3; kx++) {
            int kk = ky*3 + kx;
            #pragma unroll
            for (int cig = 0; cig < 2; cig++) {
                s16x8 ah[4], al[4];
                #pragma unroll
                for (int mf = 0; mf < 4; mf++) {
                    int xo = mf*16 + m;
                    int ix = 2*xo + kx - 1;
                    bool v = ix >= 0;
                    int ixc = v ? ix : 0;
                    size_t a = ibase + ((size_t)iy*128 + ixc)*64 + cig*32 + ks*8;
                    s16x8 zh = {0,0,0,0,0,0,0,0};
                    s16x8 th = *(const s16x8*)(A2H + a);
                    s16x8 tl = *(const s16x8*)(A2L + a);
                    ah[mf] = v ? th : zh;
                    al[mf] = v ? tl : zh;
                }
                const unsigned short* wb = W3F + (kk*2 + cig)*8192;
                #pragma unroll
                for (int nfl = 0; nfl < 2; nfl++) {
                    int nfg = w*2 + nfl;
                    s16x8 bh  = *(const s16x8*)(wb + nfg*512 + lane*8);
                    s16x8 blo = *(const s16x8*)(wb + 4096 + nfg*512 + lane*8);
                    #pragma unroll
                    for (int mf = 0; mf < 4; mf++) {
                        acc[mf][nfl] = __builtin_amdgcn_mfma_f32_16x16x32_bf16(ah[mf], bh,  acc[mf][nfl], 0, 0, 0);
                        acc[mf][nfl] = __builtin_amdgcn_mfma_f32_16x16x32_bf16(ah[mf], blo, acc[mf][nfl], 0, 0, 0);
                        acc[mf][nfl] = __builtin_amdgcn_mfma_f32_16x16x32_bf16(al[mf], bh,  acc[mf][nfl], 0, 0, 0);
                    }
                }
            }
        }
    }

    const size_t obase = ((size_t)(bl*64 + y))*64*128;
    #pragma unroll
    for (int nfl = 0; nfl < 2; nfl++) {
        int co = (w*2 + nfl)*16 + m;
        float bv = bias[co];
        #pragma unroll
        for (int mf = 0; mf < 4; mf++) {
            #pragma unroll
            for (int r = 0; r < 4; r++) {
                float rv = fmaxf(acc[mf][nfl][r] + bv, 0.f);
                unsigned short h = f2bf(rv);
                unsigned short l = f2bf(rv - bf2f(h));
                int xo = mf*16 + ks*4 + r;
                A3P[obase + (size_t)xo*128 + co] = (unsigned)h | ((unsigned)l << 16);
            }
        }
    }
}

// ---------------- MFMA head: det = split-bf16 (3 MFMA), bbox = plain bf16 (1 MFMA) --
// Only det scores feed top-k/mask (rank-sensitive); bbox logits tolerate ~0.4% rel
// error (box error ~0.2 << threshold 5.48). head is block-uniform -> clean branch.
__global__ __launch_bounds__(512, 2) void headmm_k(
    const unsigned* __restrict__ A3P, const unsigned short* __restrict__ WF,
    const float* __restrict__ db1, const float* __restrict__ dw2, const float* __restrict__ db2,
    const float* __restrict__ bb1, const float* __restrict__ bw2, const float* __restrict__ bb2,
    float* __restrict__ SC, float* __restrict__ BF, int b0)
{
    __shared__ __attribute__((aligned(16))) unsigned short Ah[8704];
    __shared__ __attribute__((aligned(16))) unsigned short Al[8704];
    __shared__ float red[8][4][64];

    const int tid  = threadIdx.x;
    const int lane = tid & 63;
    const int w    = tid >> 6;
    const int head = blockIdx.y;
    const int imgl = blockIdx.x >> 6;
    const int y    = blockIdx.x & 63;

    f32x4 acc[4][2];
    #pragma unroll
    for (int mf = 0; mf < 4; mf++)
        #pragma unroll
        for (int nf = 0; nf < 2; nf++) {
            f32x4 z = {0.f, 0.f, 0.f, 0.f};
            acc[mf][nf] = z;
        }

    const unsigned* abase = A3P + (size_t)imgl * 64 * 64 * 128;
    const unsigned short* WFh = WF + head * 589824;

    uint4 pva[2], pvb[2];
    #define HM_ISSUE(CIG)                                                          \
        _Pragma("unroll")                                                          \
        for (int it = 0; it < 2; it++) {                                           \
            int t = tid + it*512;                                                  \
            uint4 z4 = {0u,0u,0u,0u};                                              \
            pva[it] = z4; pvb[it] = z4;                                            \
            if (t < 792) {                                                         \
                int kgrp = t & 3; int q = t >> 2;                                  \
                int xi = q % 66;  int row = q / 66;                                \
                int gr = y + row - 1, gx = xi - 1;                                 \
                if (((unsigned)gr < 64u) && ((unsigned)gx < 64u)) {                \
                    const uint4* p = (const uint4*)(abase + ((size_t)gr*64 + gx)*128 \
                                                    + (CIG)*32 + kgrp*8);          \
                    pva[it] = p[0]; pvb[it] = p[1];                                \
                }                                                                  \
            }                                                                      \
        }

    HM_ISSUE(0);
    for (int cig = 0; cig < 4; cig++) {
        __syncthreads();
        #pragma unroll
        for (int it = 0; it < 2; it++) {
            int t = tid + it*512;
            if (t < 792) {
                int kgrp = t & 3; int q = t >> 2;
                int xi = q % 66;  int row = q / 66;
                int a = ((kgrp*4 + row)*68 + xi)*8;
                uint4 va = pva[it], vb = pvb[it];
                uint4 h, l;
                h.x = (va.x & 0xffffu) | (va.y << 16);
                h.y = (va.z & 0xffffu) | (va.w << 16);
                h.z = (vb.x & 0xffffu) | (vb.y << 16);
                h.w = (vb.z & 0xffffu) | (vb.w << 16);
                l.x = (va.x >> 16) | (va.y & 0xffff0000u);
                l.y = (va.z >> 16) | (va.w & 0xffff0000u);
                l.z = (vb.x >> 16) | (vb.y & 0xffff0000u);
                l.w = (vb.z >> 16) | (vb.w & 0xffff0000u);
                *(uint4*)&Ah[a] = h;
                *(uint4*)&Al[a] = l;
            }
        }
        if (cig < 3) { HM_ISSUE(cig + 1); }
        __syncthreads();
        __builtin_amdgcn_s_setprio(1);
        if (head == 0) {
            // det head: full split-bf16 (rank-critical)
            #pragma unroll 1
            for (int kk = 0; kk < 9; kk++) {
                int ky = kk / 3, kx = kk - 3*(kk/3);
                s16x8 ah[4], al[4];
                #pragma unroll
                for (int mf = 0; mf < 4; mf++) {
                    int xq = (lane & 15) + 16*mf + kx;
                    int a = (((lane >> 4)*4 + ky)*68 + xq)*8;
                    ah[mf] = *(const s16x8*)&Ah[a];
                    al[mf] = *(const s16x8*)&Al[a];
                }
                const unsigned short* wk = WFh + kk*65536 + cig*16384;
                #pragma unroll
                for (int nf = 0; nf < 2; nf++) {
                    int nfg = w*2 + nf;
                    s16x8 bh = *(const s16x8*)(wk + nfg*512 + lane*8);
                    s16x8 bl = *(const s16x8*)(wk + 8192 + nfg*512 + lane*8);
                    #pragma unroll
                    for (int mf = 0; mf < 4; mf++) {
                        acc[mf][nf] = __builtin_amdgcn_mfma_f32_16x16x32_bf16(ah[mf], bh, acc[mf][nf], 0, 0, 0);
                        acc[mf][nf] = __builtin_amdgcn_mfma_f32_16x16x32_bf16(ah[mf], bl, acc[mf][nf], 0, 0, 0);
                        acc[mf][nf] = __builtin_amdgcn_mfma_f32_16x16x32_bf16(al[mf], bh, acc[mf][nf], 0, 0, 0);
                    }
                }
            }
        } else {
            // bbox head: plain bf16 (1 MFMA) — error ~0.2 on boxes, threshold 5.48
            #pragma unroll 1
            for (int kk = 0; kk < 9; kk++) {
                int ky = kk / 3, kx = kk - 3*(kk/3);
                s16x8 ah[4];
                #pragma unroll
                for (int mf = 0; mf < 4; mf++) {
                    int xq = (lane & 15) + 16*mf + kx;
                    int a = (((lane >> 4)*4 + ky)*68 + xq)*8;
                    ah[mf] = *(const s16x8*)&Ah[a];
                }
                const unsigned short* wk = WFh + kk*65536 + cig*16384;
                #pragma unroll
                for (int nf = 0; nf < 2; nf++) {
                    int nfg = w*2 + nf;
                    s16x8 bh = *(const s16x8*)(wk + nfg*512 + lane*8);
                    #pragma unroll
                    for (int mf = 0; mf < 4; mf++)
                        acc[mf][nf] = __builtin_amdgcn_mfma_f32_16x16x32_bf16(ah[mf], bh, acc[mf][nf], 0, 0, 0);
                }
            }
        }
        __builtin_amdgcn_s_setprio(0);
    }
    #undef HM_ISSUE

    const float* b1p = head ? bb1 : db1;
    const float* w2p = head ? bw2 : dw2;
    const float* b2p = head ? bb2 : db2;
    const int NOUT = head ? 4 : 1;

    #pragma unroll
    for (int nf = 0; nf < 2; nf++) {
        float bv = b1p[(lane & 15) + (w*2 + nf)*16];
        #pragma unroll
        for (int mf = 0; mf < 4; mf++)
            #pragma unroll
            for (int r = 0; r < 4; r++)
                acc[mf][nf][r] = fmaxf(acc[mf][nf][r] + bv, 0.f);
    }

    for (int p = 0; p < NOUT; p++) {
        float wq0 = w2p[p*256 + (lane & 15) + (w*2 + 0)*16];
        float wq1 = w2p[p*256 + (lane & 15) + (w*2 + 1)*16];
        #pragma unroll
        for (int mf = 0; mf < 4; mf++) {
            #pragma unroll
            for (int r = 0; r < 4; r++) {
                float v = acc[mf][0][r]*wq0 + acc[mf][1][r]*wq1;
                v += __shfl_xor(v, 1);
                v += __shfl_xor(v, 2);
                v += __shfl_xor(v, 4);
                v += __shfl_xor(v, 8);
                if ((lane & 15) == 0)
                    red[w][p][mf*16 + (lane >> 4)*4 + r] = v;
            }
        }
    }
    __syncthreads();
    float* outp = head ? BF : SC;
    if (tid < NOUT*64) {
        int p = tid >> 6; int px = tid & 63;
        float v = b2p[p];
        #pragma unroll
        for (int ww = 0; ww < 8; ww++) v += red[ww][p][px];
        outp[((size_t)((b0 + imgl)*NOUT + p))*4096 + y*64 + px] = v;
    }
}

__global__ __launch_bounds__(256) void topk_k(
    const float* __restrict__ scores, const float* __restrict__ bflat,
    float* __restrict__ outp)
{
    __shared__ float sv[4096];
    __shared__ float rv[256];
    __shared__ int   ri[256];
    __shared__ float kv[8];
    __shared__ int   kidx[8];
    int b = blockIdx.x, t = threadIdx.x;
    for (int i = t; i < 4096; i += 256) sv[i] = scores[b*4096 + i];
    __syncthreads();
    for (int k = 0; k < 8; k++) {
        float bv = -INFINITY; int bi = 0x7fffffff;
        for (int i = t; i < 4096; i += 256) {
            float v = sv[i];
            if (v > bv || (v == bv && i < bi)) { bv = v; bi = i; }
        }
        rv[t] = bv; ri[t] = bi;
        __syncthreads();
        for (int s = 128; s > 0; s >>= 1) {
            if (t < s) {
                float v2 = rv[t+s]; int i2 = ri[t+s];
                if (v2 > rv[t] || (v2 == rv[t] && i2 < ri[t])) { rv[t] = v2; ri[t] = i2; }
            }
            __syncthreads();
        }
        if (t == 0) { kv[k] = rv[0]; kidx[k] = ri[0]; sv[ri[0]] = -INFINITY; }
        __syncthreads();
    }
    if (t < 32) {
        int k = t >> 2, c = t & 3;
        int idx = kidx[k];
        float s  = 1.f / (1.f + expf(-kv[k]));
        float lg = bflat[((size_t)(b*4 + c))*4096 + idx];
        float box = 512.f / (1.f + expf(-lg));
        outp[(b*8 + k)*4 + c] = (s > 0.5f) ? box : 0.f;
    }
}

extern "C" void kernel_launch(void* const* d_in, const int* in_sizes, int n_in,
                              void* d_out, int out_size, void* d_ws, size_t ws_size,
                              hipStream_t stream)
{
    const float* x   = (const float*)d_in[0];
    const float* w1  = (const float*)d_in[1];
    const float* b1  = (const float*)d_in[2];
    const float* g1  = (const float*)d_in[3];
    const float* be1 = (const float*)d_in[4];
    const float* m1  = (const float*)d_in[5];
    const float* v1  = (const float*)d_in[6];
    const float* w2  = (const float*)d_in[7];
    const float* b2  = (const float*)d_in[8];
    const float* g2  = (const float*)d_in[9];
    const float* be2 = (const float*)d_in[10];
    const float* m2  = (const float*)d_in[11];
    const float* v2  = (const float*)d_in[12];
    const float* w3  = (const float*)d_in[13];
    const float* b3  = (const float*)d_in[14];
    const float* g3  = (const float*)d_in[15];
    const float* be3 = (const float*)d_in[16];
    const float* m3  = (const float*)d_in[17];
    const float* v3  = (const float*)d_in[18];
    const float* dw1 = (const float*)d_in[19];
    const float* db1 = (const float*)d_in[20];
    const float* dw2 = (const float*)d_in[21];
    const float* db2 = (const float*)d_in[22];
    const float* bw1 = (const float*)d_in[23];
    const float* bb1 = (const float*)d_in[24];
    const float* bw2 = (const float*)d_in[25];
    const float* bb2 = (const float*)d_in[26];

    char*  wsb = (char*)d_ws;
    float*          W   = (float*)wsb;
    unsigned short* WF  = (unsigned short*)(wsb + 372992);
    unsigned short* W3F = (unsigned short*)(wsb + 2732288);
    float*          SC  = (float*)(wsb + 3027200);
    float*          BF  = (float*)(wsb + 3551488);
    unsigned short* A2H = (unsigned short*)(wsb + 5648640);
    unsigned short* A2L = (unsigned short*)(wsb + 22425856);
    unsigned*       A3P = (unsigned*)(wsb + 39203072);
    unsigned short* W2F = (unsigned short*)(wsb + 55980288);
    float* out = (float*)d_out;

    prep_k <<<365, 256, 0, stream>>>(w1,b1,g1,be1,m1,v1, w2,b2,g2,be2,m2,v2,
                                     w3,b3,g3,be3,m3,v3, W);
    prep2_k<<<4608, 256, 0, stream>>>(dw1, bw1, WF);
    prep3_k<<<576, 256, 0, stream>>>(w3, g3, v3, W3F);
    prep4_k<<<144, 256, 0, stream>>>(w2, g2, v2, W2F);

    for (int c = 0; c < 4; c++) {
        conv12mm_k<<<2048, 256, 0, stream>>>(x, W, W2F, A2H, A2L, c*8);
        conv3mm_k <<<512, 256, 0, stream>>>(A2H, A2L, W3F, W + 93120, A3P);
        headmm_k  <<<dim3(512, 2), 512, 0, stream>>>(A3P, WF, db1, dw2, db2, bb1, bw2, bb2,
                                                     SC, BF, c*8);
    }
    topk_k<<<32, 256, 0, stream>>>(SC, BF, out);
}

// Round 19
// 603.507 us; speedup vs baseline: 1.3307x; 1.0767x over previous
//
#include <hip/hip_runtime.h>
#include <math.h>

#define EPSBN 1e-5f

typedef __attribute__((ext_vector_type(4))) float f32x4;
typedef __attribute__((ext_vector_type(8))) short s16x8;

__device__ __forceinline__ unsigned short f2bf(float f) {
    unsigned u = __builtin_bit_cast(unsigned, f);
    u = (u + 0x7fffu + ((u >> 16) & 1u)) >> 16;
    return (unsigned short)u;
}
__device__ __forceinline__ float bf2f(unsigned short s) {
    unsigned u = ((unsigned)s) << 16;
    return __builtin_bit_cast(float, u);
}

// ---------------- workspace layout (BYTE offsets) -----------------------------------
// fixed: W @0 | WF @372,992 | W3F @2,732,288 | W2F @3,027,200 | SC @3,100,928
//        BF @3,625,216 | fixed end @5,722,368
// per-chunk (C images, chosen at launch from ws_size):
//        A2H @5,722,368 (C*2MB) | A2L (+C*2MB) | A3P (+C*2MB)
// peak(C) = 5,722,368 + 6*C MB;  C=8 -> 56.0 MB (proven safe)

__global__ __launch_bounds__(256) void prep_k(
    const float* __restrict__ w1, const float* __restrict__ b1, const float* __restrict__ g1,
    const float* __restrict__ be1, const float* __restrict__ m1, const float* __restrict__ v1,
    const float* __restrict__ w2, const float* __restrict__ b2, const float* __restrict__ g2,
    const float* __restrict__ be2, const float* __restrict__ m2, const float* __restrict__ v2,
    const float* __restrict__ w3, const float* __restrict__ b3, const float* __restrict__ g3,
    const float* __restrict__ be3, const float* __restrict__ m3, const float* __restrict__ v3,
    float* __restrict__ W)
{
    int i = blockIdx.x * 256 + threadIdx.x;
    if (i < 864) {
        int co = i & 31; int r = i >> 5; int ci = r % 3; int kk = r / 3;
        float A = g1[co] * rsqrtf(v1[co] + EPSBN);
        W[i] = w1[(co*3 + ci)*9 + kk] * A;
    } else if (i < 896) {
        int co = i - 864;
        float A = g1[co] * rsqrtf(v1[co] + EPSBN);
        W[i] = (b1[co] - m1[co]) * A + be1[co];
    } else if (i >= 19328 && i < 19392) {
        int co = i - 19328;
        float A = g2[co] * rsqrtf(v2[co] + EPSBN);
        W[i] = (b2[co] - m2[co]) * A + be2[co];
    } else if (i >= 93120 && i < 93248) {
        int co = i - 93120;
        float A = g3[co] * rsqrtf(v3[co] + EPSBN);
        W[i] = (b3[co] - m3[co]) * A + be3[co];
    }
}

__global__ __launch_bounds__(256) void prep2_k(
    const float* __restrict__ dw1, const float* __restrict__ bw1,
    unsigned short* __restrict__ WF)
{
    int i = blockIdx.x * 256 + threadIdx.x;
    if (i >= 1179648) return;
    int head = i / 589824;
    int r    = i - head * 589824;
    int kk   = r >> 16;
    int r2   = r & 65535;
    int cig  = r2 >> 14;
    int pl   = (r2 >> 13) & 1;
    int nf   = (r2 >> 9) & 15;
    int lane = (r2 >> 3) & 63;
    int j    = r2 & 7;
    int ci = cig*32 + (lane >> 4)*8 + j;
    int co = (lane & 15) + nf*16;
    const float* src = head ? bw1 : dw1;
    float w = src[(co*128 + ci)*9 + kk];
    unsigned short h = f2bf(w);
    WF[i] = pl ? f2bf(w - bf2f(h)) : h;
}

__global__ __launch_bounds__(256) void prep3_k(
    const float* __restrict__ w3, const float* __restrict__ g3, const float* __restrict__ v3,
    unsigned short* __restrict__ W3F)
{
    int i = blockIdx.x * 256 + threadIdx.x;
    if (i >= 147456) return;
    int kk = i >> 14;
    int r  = i & 16383;
    int cig = r >> 13;
    int pl  = (r >> 12) & 1;
    int nf  = (r >> 9) & 7;
    int lane = (r >> 3) & 63;
    int j   = r & 7;
    int ci = cig*32 + (lane >> 4)*8 + j;
    int co = nf*16 + (lane & 15);
    float A = g3[co] * rsqrtf(v3[co] + EPSBN);
    float w = w3[(co*64 + ci)*9 + kk] * A;
    unsigned short h = f2bf(w);
    W3F[i] = pl ? f2bf(w - bf2f(h)) : h;
}

__global__ __launch_bounds__(256) void prep4_k(
    const float* __restrict__ w2, const float* __restrict__ g2, const float* __restrict__ v2,
    unsigned short* __restrict__ W2F)
{
    int i = blockIdx.x * 256 + threadIdx.x;
    if (i >= 36864) return;
    int kk = i >> 12;
    int r  = i & 4095;
    int pl  = r >> 11;
    int nfg = (r >> 9) & 3;
    int lane = (r >> 3) & 63;
    int j   = r & 7;
    int ci = (lane >> 4)*8 + j;
    int co = nfg*16 + (lane & 15);
    float A = g2[co] * rsqrtf(v2[co] + EPSBN);
    float w = w2[(co*32 + ci)*9 + kk] * A;
    unsigned short h = f2bf(w);
    W2F[i] = pl ? f2bf(w - bf2f(h)) : h;
}

// ---------------- fused conv1(VALU)+conv2(MFMA): 16x4 tile, 256 tiles/img -----------
__global__ __launch_bounds__(256, 4) void conv12mm_k(
    const float* __restrict__ x, const float* __restrict__ W,
    const unsigned short* __restrict__ W2F,
    unsigned short* __restrict__ A2H, unsigned short* __restrict__ A2L, int b0)
{
    __shared__ __attribute__((aligned(16))) unsigned short Ah[9792];
    __shared__ __attribute__((aligned(16))) unsigned short Al[9792];

    const int tid  = threadIdx.x;
    const int lane = tid & 63;
    const int wv   = tid >> 6;
    const int m    = lane & 15;
    const int ks   = lane >> 4;

    const int bl   = blockIdx.x >> 8;
    const int tile = blockIdx.x & 255;
    const int OY = (tile >> 3) * 4;
    const int OX = (tile & 7) * 16;
    const int base1y = 2*OY - 1, base1x = 2*OX - 1;

    const float* xb = x + (size_t)(b0 + bl) * 3 * 262144;

    for (int t = tid; t < 297; t += 256) {
        int row = t / 33, lx = t - row*33;
        int y1 = base1y + row, x1 = base1x + lx;
        float c1[32];
        #pragma unroll
        for (int c = 0; c < 32; c++) c1[c] = 0.f;
        if (((unsigned)y1 < 256u) && ((unsigned)x1 < 256u)) {
            #pragma unroll
            for (int ky = 0; ky < 3; ky++) {
                int xy = 2*y1 + ky - 1;
                if ((unsigned)xy < 512u) {
                    #pragma unroll
                    for (int kx = 0; kx < 3; kx++) {
                        int xx = 2*x1 + kx - 1;
                        if ((unsigned)xx < 512u) {
                            int kk = ky*3 + kx;
                            #pragma unroll
                            for (int ci = 0; ci < 3; ci++) {
                                float v = xb[(size_t)ci*262144 + xy*512 + xx];
                                const float4* w4 = (const float4*)(W + (kk*3+ci)*32);
                                float4 wa = w4[0], wb = w4[1], wc = w4[2], wd = w4[3];
                                float4 we = w4[4], wf = w4[5], wg = w4[6], wh = w4[7];
                                c1[0]  = fmaf(v, wa.x, c1[0]);  c1[1]  = fmaf(v, wa.y, c1[1]);
                                c1[2]  = fmaf(v, wa.z, c1[2]);  c1[3]  = fmaf(v, wa.w, c1[3]);
                                c1[4]  = fmaf(v, wb.x, c1[4]);  c1[5]  = fmaf(v, wb.y, c1[5]);
                                c1[6]  = fmaf(v, wb.z, c1[6]);  c1[7]  = fmaf(v, wb.w, c1[7]);
                                c1[8]  = fmaf(v, wc.x, c1[8]);  c1[9]  = fmaf(v, wc.y, c1[9]);
                                c1[10] = fmaf(v, wc.z, c1[10]); c1[11] = fmaf(v, wc.w, c1[11]);
                                c1[12] = fmaf(v, wd.x, c1[12]); c1[13] = fmaf(v, wd.y, c1[13]);
                                c1[14] = fmaf(v, wd.z, c1[14]); c1[15] = fmaf(v, wd.w, c1[15]);
                                c1[16] = fmaf(v, we.x, c1[16]); c1[17] = fmaf(v, we.y, c1[17]);
                                c1[18] = fmaf(v, we.z, c1[18]); c1[19] = fmaf(v, we.w, c1[19]);
                                c1[20] = fmaf(v, wf.x, c1[20]); c1[21] = fmaf(v, wf.y, c1[21]);
                                c1[22] = fmaf(v, wf.z, c1[22]); c1[23] = fmaf(v, wf.w, c1[23]);
                                c1[24] = fmaf(v, wg.x, c1[24]); c1[25] = fmaf(v, wg.y, c1[25]);
                                c1[26] = fmaf(v, wg.z, c1[26]); c1[27] = fmaf(v, wg.w, c1[27]);
                                c1[28] = fmaf(v, wh.x, c1[28]); c1[29] = fmaf(v, wh.y, c1[29]);
                                c1[30] = fmaf(v, wh.z, c1[30]); c1[31] = fmaf(v, wh.w, c1[31]);
                            }
                        }
                    }
                }
            }
            #pragma unroll
            for (int c = 0; c < 32; c++)
                c1[c] = fmaxf(c1[c] + W[864 + c], 0.f);
        }
        int xi = (lx & 1)*17 + (lx >> 1);
        #pragma unroll
        for (int kg = 0; kg < 4; kg++) {
            uint4 h, l;
            unsigned hw[4], lw[4];
            #pragma unroll
            for (int q = 0; q < 4; q++) {
                float r0 = c1[kg*8 + 2*q], r1 = c1[kg*8 + 2*q + 1];
                unsigned short h0 = f2bf(r0), h1 = f2bf(r1);
                unsigned short l0 = f2bf(r0 - bf2f(h0)), l1 = f2bf(r1 - bf2f(h1));
                hw[q] = (unsigned)h0 | ((unsigned)h1 << 16);
                lw[q] = (unsigned)l0 | ((unsigned)l1 << 16);
            }
            h.x = hw[0]; h.y = hw[1]; h.z = hw[2]; h.w = hw[3];
            l.x = lw[0]; l.y = lw[1]; l.z = lw[2]; l.w = lw[3];
            int a = ((kg*9 + row)*34 + xi)*8;
            *(uint4*)&Ah[a] = h;
            *(uint4*)&Al[a] = l;
        }
    }
    __syncthreads();

    f32x4 acc[4];
    #pragma unroll
    for (int mf = 0; mf < 4; mf++) { f32x4 z = {0.f,0.f,0.f,0.f}; acc[mf] = z; }

    for (int ky = 0; ky < 3; ky++) {
        for (int kx = 0; kx < 3; kx++) {
            int kk = ky*3 + kx;
            int xib = (kx & 1)*17 + (kx >> 1);
            s16x8 ah[4], al[4];
            #pragma unroll
            for (int mf = 0; mf < 4; mf++) {
                int hy = 2*mf + ky;
                int a = ((ks*9 + hy)*34 + xib + m)*8;
                ah[mf] = *(const s16x8*)&Ah[a];
                al[mf] = *(const s16x8*)&Al[a];
            }
            const unsigned short* wb = W2F + kk*4096;
            s16x8 bh  = *(const s16x8*)(wb + wv*512 + lane*8);
            s16x8 blo = *(const s16x8*)(wb + 2048 + wv*512 + lane*8);
            #pragma unroll
            for (int mf = 0; mf < 4; mf++) {
                acc[mf] = __builtin_amdgcn_mfma_f32_16x16x32_bf16(ah[mf], bh,  acc[mf], 0, 0, 0);
                acc[mf] = __builtin_amdgcn_mfma_f32_16x16x32_bf16(ah[mf], blo, acc[mf], 0, 0, 0);
                acc[mf] = __builtin_amdgcn_mfma_f32_16x16x32_bf16(al[mf], bh,  acc[mf], 0, 0, 0);
            }
        }
    }

    const int co = wv*16 + m;
    const float bv = W[19328 + co];
    #pragma unroll
    for (int mf = 0; mf < 4; mf++) {
        int y = OY + mf;
        #pragma unroll
        for (int r = 0; r < 4; r++) {
            int xo = OX + ks*4 + r;
            float rv = fmaxf(acc[mf][r] + bv, 0.f);
            unsigned short h = f2bf(rv);
            unsigned short l = f2bf(rv - bf2f(h));
            size_t a = ((size_t)(bl*16384 + y*128 + xo))*64 + co;
            A2H[a] = h;
            A2L[a] = l;
        }
    }
}

// ---------------- conv3 MFMA: full row per block, 64 blocks/img ---------------------
__global__ __launch_bounds__(256, 2) void conv3mm_k(
    const unsigned short* __restrict__ A2H, const unsigned short* __restrict__ A2L,
    const unsigned short* __restrict__ W3F, const float* __restrict__ bias,
    unsigned* __restrict__ A3P)
{
    const int tid  = threadIdx.x;
    const int lane = tid & 63;
    const int w    = tid >> 6;
    const int bl   = blockIdx.x >> 6;
    const int y    = blockIdx.x & 63;
    const int m    = lane & 15;
    const int ks   = lane >> 4;

    f32x4 acc[4][2];
    #pragma unroll
    for (int mf = 0; mf < 4; mf++)
        #pragma unroll
        for (int nfl = 0; nfl < 2; nfl++) {
            f32x4 z = {0.f, 0.f, 0.f, 0.f};
            acc[mf][nfl] = z;
        }

    const size_t ibase = (size_t)bl * 16384 * 64;

    for (int ky = 0; ky < 3; ky++) {
        int iy = 2*y + ky - 1;
        if ((unsigned)iy >= 128u) continue;
        for (int kx = 0; kx < 3; kx++) {
            int kk = ky*3 + kx;
            #pragma unroll
            for (int cig = 0; cig < 2; cig++) {
                s16x8 ah[4], al[4];
                #pragma unroll
                for (int mf = 0; mf < 4; mf++) {
                    int xo = mf*16 + m;
                    int ix = 2*xo + kx - 1;
                    bool v = ix >= 0;
                    int ixc = v ? ix : 0;
                    size_t a = ibase + ((size_t)iy*128 + ixc)*64 + cig*32 + ks*8;
                    s16x8 zh = {0,0,0,0,0,0,0,0};
                    s16x8 th = *(const s16x8*)(A2H + a);
                    s16x8 tl = *(const s16x8*)(A2L + a);
                    ah[mf] = v ? th : zh;
                    al[mf] = v ? tl : zh;
                }
                const unsigned short* wb = W3F + (kk*2 + cig)*8192;
                #pragma unroll
                for (int nfl = 0; nfl < 2; nfl++) {
                    int nfg = w*2 + nfl;
                    s16x8 bh  = *(const s16x8*)(wb + nfg*512 + lane*8);
                    s16x8 blo = *(const s16x8*)(wb + 4096 + nfg*512 + lane*8);
                    #pragma unroll
                    for (int mf = 0; mf < 4; mf++) {
                        acc[mf][nfl] = __builtin_amdgcn_mfma_f32_16x16x32_bf16(ah[mf], bh,  acc[mf][nfl], 0, 0, 0);
                        acc[mf][nfl] = __builtin_amdgcn_mfma_f32_16x16x32_bf16(ah[mf], blo, acc[mf][nfl], 0, 0, 0);
                        acc[mf][nfl] = __builtin_amdgcn_mfma_f32_16x16x32_bf16(al[mf], bh,  acc[mf][nfl], 0, 0, 0);
                    }
                }
            }
        }
    }

    const size_t obase = ((size_t)(bl*64 + y))*64*128;
    #pragma unroll
    for (int nfl = 0; nfl < 2; nfl++) {
        int co = (w*2 + nfl)*16 + m;
        float bv = bias[co];
        #pragma unroll
        for (int mf = 0; mf < 4; mf++) {
            #pragma unroll
            for (int r = 0; r < 4; r++) {
                float rv = fmaxf(acc[mf][nfl][r] + bv, 0.f);
                unsigned short h = f2bf(rv);
                unsigned short l = f2bf(rv - bf2f(h));
                int xo = mf*16 + ks*4 + r;
                A3P[obase + (size_t)xo*128 + co] = (unsigned)h | ((unsigned)l << 16);
            }
        }
    }
}

// ---------------- MFMA head: det = split-bf16 (3 MFMA), bbox = plain bf16 (1 MFMA) --
// bbox blocks also skip the Al LDS writes (never read them).
__global__ __launch_bounds__(512, 2) void headmm_k(
    const unsigned* __restrict__ A3P, const unsigned short* __restrict__ WF,
    const float* __restrict__ db1, const float* __restrict__ dw2, const float* __restrict__ db2,
    const float* __restrict__ bb1, const float* __restrict__ bw2, const float* __restrict__ bb2,
    float* __restrict__ SC, float* __restrict__ BF, int b0)
{
    __shared__ __attribute__((aligned(16))) unsigned short Ah[8704];
    __shared__ __attribute__((aligned(16))) unsigned short Al[8704];
    __shared__ float red[8][4][64];

    const int tid  = threadIdx.x;
    const int lane = tid & 63;
    const int w    = tid >> 6;
    const int head = blockIdx.y;
    const int imgl = blockIdx.x >> 6;
    const int y    = blockIdx.x & 63;

    f32x4 acc[4][2];
    #pragma unroll
    for (int mf = 0; mf < 4; mf++)
        #pragma unroll
        for (int nf = 0; nf < 2; nf++) {
            f32x4 z = {0.f, 0.f, 0.f, 0.f};
            acc[mf][nf] = z;
        }

    const unsigned* abase = A3P + (size_t)imgl * 64 * 64 * 128;
    const unsigned short* WFh = WF + head * 589824;

    uint4 pva[2], pvb[2];
    #define HM_ISSUE(CIG)                                                          \
        _Pragma("unroll")                                                          \
        for (int it = 0; it < 2; it++) {                                           \
            int t = tid + it*512;                                                  \
            uint4 z4 = {0u,0u,0u,0u};                                              \
            pva[it] = z4; pvb[it] = z4;                                            \
            if (t < 792) {                                                         \
                int kgrp = t & 3; int q = t >> 2;                                  \
                int xi = q % 66;  int row = q / 66;                                \
                int gr = y + row - 1, gx = xi - 1;                                 \
                if (((unsigned)gr < 64u) && ((unsigned)gx < 64u)) {                \
                    const uint4* p = (const uint4*)(abase + ((size_t)gr*64 + gx)*128 \
                                                    + (CIG)*32 + kgrp*8);          \
                    pva[it] = p[0]; pvb[it] = p[1];                                \
                }                                                                  \
            }                                                                      \
        }

    HM_ISSUE(0);
    for (int cig = 0; cig < 4; cig++) {
        __syncthreads();
        #pragma unroll
        for (int it = 0; it < 2; it++) {
            int t = tid + it*512;
            if (t < 792) {
                int kgrp = t & 3; int q = t >> 2;
                int xi = q % 66;  int row = q / 66;
                int a = ((kgrp*4 + row)*68 + xi)*8;
                uint4 va = pva[it], vb = pvb[it];
                uint4 h;
                h.x = (va.x & 0xffffu) | (va.y << 16);
                h.y = (va.z & 0xffffu) | (va.w << 16);
                h.z = (vb.x & 0xffffu) | (vb.y << 16);
                h.w = (vb.z & 0xffffu) | (vb.w << 16);
                *(uint4*)&Ah[a] = h;
                if (head == 0) {
                    uint4 l;
                    l.x = (va.x >> 16) | (va.y & 0xffff0000u);
                    l.y = (va.z >> 16) | (va.w & 0xffff0000u);
                    l.z = (vb.x >> 16) | (vb.y & 0xffff0000u);
                    l.w = (vb.z >> 16) | (vb.w & 0xffff0000u);
                    *(uint4*)&Al[a] = l;
                }
            }
        }
        if (cig < 3) { HM_ISSUE(cig + 1); }
        __syncthreads();
        __builtin_amdgcn_s_setprio(1);
        if (head == 0) {
            #pragma unroll 1
            for (int kk = 0; kk < 9; kk++) {
                int ky = kk / 3, kx = kk - 3*(kk/3);
                s16x8 ah[4], al[4];
                #pragma unroll
                for (int mf = 0; mf < 4; mf++) {
                    int xq = (lane & 15) + 16*mf + kx;
                    int a = (((lane >> 4)*4 + ky)*68 + xq)*8;
                    ah[mf] = *(const s16x8*)&Ah[a];
                    al[mf] = *(const s16x8*)&Al[a];
                }
                const unsigned short* wk = WFh + kk*65536 + cig*16384;
                #pragma unroll
                for (int nf = 0; nf < 2; nf++) {
                    int nfg = w*2 + nf;
                    s16x8 bh = *(const s16x8*)(wk + nfg*512 + lane*8);
                    s16x8 bl = *(const s16x8*)(wk + 8192 + nfg*512 + lane*8);
                    #pragma unroll
                    for (int mf = 0; mf < 4; mf++) {
                        acc[mf][nf] = __builtin_amdgcn_mfma_f32_16x16x32_bf16(ah[mf], bh, acc[mf][nf], 0, 0, 0);
                        acc[mf][nf] = __builtin_amdgcn_mfma_f32_16x16x32_bf16(ah[mf], bl, acc[mf][nf], 0, 0, 0);
                        acc[mf][nf] = __builtin_amdgcn_mfma_f32_16x16x32_bf16(al[mf], bh, acc[mf][nf], 0, 0, 0);
                    }
                }
            }
        } else {
            #pragma unroll 1
            for (int kk = 0; kk < 9; kk++) {
                int ky = kk / 3, kx = kk - 3*(kk/3);
                s16x8 ah[4];
                #pragma unroll
                for (int mf = 0; mf < 4; mf++) {
                    int xq = (lane & 15) + 16*mf + kx;
                    int a = (((lane >> 4)*4 + ky)*68 + xq)*8;
                    ah[mf] = *(const s16x8*)&Ah[a];
                }
                const unsigned short* wk = WFh + kk*65536 + cig*16384;
                #pragma unroll
                for (int nf = 0; nf < 2; nf++) {
                    int nfg = w*2 + nf;
                    s16x8 bh = *(const s16x8*)(wk + nfg*512 + lane*8);
                    #pragma unroll
                    for (int mf = 0; mf < 4; mf++)
                        acc[mf][nf] = __builtin_amdgcn_mfma_f32_16x16x32_bf16(ah[mf], bh, acc[mf][nf], 0, 0, 0);
                }
            }
        }
        __builtin_amdgcn_s_setprio(0);
    }
    #undef HM_ISSUE

    const float* b1p = head ? bb1 : db1;
    const float* w2p = head ? bw2 : dw2;
    const float* b2p = head ? bb2 : db2;
    const int NOUT = head ? 4 : 1;

    #pragma unroll
    for (int nf = 0; nf < 2; nf++) {
        float bv = b1p[(lane & 15) + (w*2 + nf)*16];
        #pragma unroll
        for (int mf = 0; mf < 4; mf++)
            #pragma unroll
            for (int r = 0; r < 4; r++)
                acc[mf][nf][r] = fmaxf(acc[mf][nf][r] + bv, 0.f);
    }

    for (int p = 0; p < NOUT; p++) {
        float wq0 = w2p[p*256 + (lane & 15) + (w*2 + 0)*16];
        float wq1 = w2p[p*256 + (lane & 15) + (w*2 + 1)*16];
        #pragma unroll
        for (int mf = 0; mf < 4; mf++) {
            #pragma unroll
            for (int r = 0; r < 4; r++) {
                float v = acc[mf][0][r]*wq0 + acc[mf][1][r]*wq1;
                v += __shfl_xor(v, 1);
                v += __shfl_xor(v, 2);
                v += __shfl_xor(v, 4);
                v += __shfl_xor(v, 8);
                if ((lane & 15) == 0)
                    red[w][p][mf*16 + (lane >> 4)*4 + r] = v;
            }
        }
    }
    __syncthreads();
    float* outp = head ? BF : SC;
    if (tid < NOUT*64) {
        int p = tid >> 6; int px = tid & 63;
        float v = b2p[p];
        #pragma unroll
        for (int ww = 0; ww < 8; ww++) v += red[ww][p][px];
        outp[((size_t)((b0 + imgl)*NOUT + p))*4096 + y*64 + px] = v;
    }
}

__global__ __launch_bounds__(256) void topk_k(
    const float* __restrict__ scores, const float* __restrict__ bflat,
    float* __restrict__ outp)
{
    __shared__ float sv[4096];
    __shared__ float rv[256];
    __shared__ int   ri[256];
    __shared__ float kv[8];
    __shared__ int   kidx[8];
    int b = blockIdx.x, t = threadIdx.x;
    for (int i = t; i < 4096; i += 256) sv[i] = scores[b*4096 + i];
    __syncthreads();
    for (int k = 0; k < 8; k++) {
        float bv = -INFINITY; int bi = 0x7fffffff;
        for (int i = t; i < 4096; i += 256) {
            float v = sv[i];
            if (v > bv || (v == bv && i < bi)) { bv = v; bi = i; }
        }
        rv[t] = bv; ri[t] = bi;
        __syncthreads();
        for (int s = 128; s > 0; s >>= 1) {
            if (t < s) {
                float v2 = rv[t+s]; int i2 = ri[t+s];
                if (v2 > rv[t] || (v2 == rv[t] && i2 < ri[t])) { rv[t] = v2; ri[t] = i2; }
            }
            __syncthreads();
        }
        if (t == 0) { kv[k] = rv[0]; kidx[k] = ri[0]; sv[ri[0]] = -INFINITY; }
        __syncthreads();
    }
    if (t < 32) {
        int k = t >> 2, c = t & 3;
        int idx = kidx[k];
        float s  = 1.f / (1.f + expf(-kv[k]));
        float lg = bflat[((size_t)(b*4 + c))*4096 + idx];
        float box = 512.f / (1.f + expf(-lg));
        outp[(b*8 + k)*4 + c] = (s > 0.5f) ? box : 0.f;
    }
}

extern "C" void kernel_launch(void* const* d_in, const int* in_sizes, int n_in,
                              void* d_out, int out_size, void* d_ws, size_t ws_size,
                              hipStream_t stream)
{
    const float* x   = (const float*)d_in[0];
    const float* w1  = (const float*)d_in[1];
    const float* b1  = (const float*)d_in[2];
    const float* g1  = (const float*)d_in[3];
    const float* be1 = (const float*)d_in[4];
    const float* m1  = (const float*)d_in[5];
    const float* v1  = (const float*)d_in[6];
    const float* w2  = (const float*)d_in[7];
    const float* b2  = (const float*)d_in[8];
    const float* g2  = (const float*)d_in[9];
    const float* be2 = (const float*)d_in[10];
    const float* m2  = (const float*)d_in[11];
    const float* v2  = (const float*)d_in[12];
    const float* w3  = (const float*)d_in[13];
    const float* b3  = (const float*)d_in[14];
    const float* g3  = (const float*)d_in[15];
    const float* be3 = (const float*)d_in[16];
    const float* m3  = (const float*)d_in[17];
    const float* v3  = (const float*)d_in[18];
    const float* dw1 = (const float*)d_in[19];
    const float* db1 = (const float*)d_in[20];
    const float* dw2 = (const float*)d_in[21];
    const float* db2 = (const float*)d_in[22];
    const float* bw1 = (const float*)d_in[23];
    const float* bb1 = (const float*)d_in[24];
    const float* bw2 = (const float*)d_in[25];
    const float* bb2 = (const float*)d_in[26];

    char*  wsb = (char*)d_ws;
    float*          W   = (float*)wsb;
    unsigned short* WF  = (unsigned short*)(wsb + 372992);
    unsigned short* W3F = (unsigned short*)(wsb + 2732288);
    unsigned short* W2F = (unsigned short*)(wsb + 3027200);
    float*          SC  = (float*)(wsb + 3100928);
    float*          BF  = (float*)(wsb + 3625216);
    float* out = (float*)d_out;

    // chunk size chosen from ws_size (constant across calls -> deterministic)
    const size_t FIXED = 5722368;
    const size_t PERIMG = 3ull * 2097152;            // A2H + A2L + A3P per image
    int C = 8;
    if (ws_size >= FIXED + 32*PERIMG)      C = 32;
    else if (ws_size >= FIXED + 16*PERIMG) C = 16;

    unsigned short* A2H = (unsigned short*)(wsb + FIXED);
    unsigned short* A2L = (unsigned short*)(wsb + FIXED + (size_t)C*2097152);
    unsigned*       A3P = (unsigned*)(wsb + FIXED + (size_t)C*2097152*2);

    prep_k <<<365, 256, 0, stream>>>(w1,b1,g1,be1,m1,v1, w2,b2,g2,be2,m2,v2,
                                     w3,b3,g3,be3,m3,v3, W);
    prep2_k<<<4608, 256, 0, stream>>>(dw1, bw1, WF);
    prep3_k<<<576, 256, 0, stream>>>(w3, g3, v3, W3F);
    prep4_k<<<144, 256, 0, stream>>>(w2, g2, v2, W2F);

    for (int c = 0; c < 32/C; c++) {
        conv12mm_k<<<C*256, 256, 0, stream>>>(x, W, W2F, A2H, A2L, c*C);
        conv3mm_k <<<C*64, 256, 0, stream>>>(A2H, A2L, W3F, W + 93120, A3P);
        headmm_k  <<<dim3(C*64, 2), 512, 0, stream>>>(A3P, WF, db1, dw2, db2, bb1, bw2, bb2,
                                                      SC, BF, c*C);
    }
    topk_k<<<32, 256, 0, stream>>>(SC, BF, out);
}